// Round 17
// baseline (251.075 us; speedup 1.0000x reference)
//
#include <hip/hip_runtime.h>
#include <math.h>

#define HH 50     // hidden features
#define BSH 8     // bucket shift: 256 nodes per bucket
#define BSZ 256
#define CH 8192   // edges per chunk in bucketed CSR build (LDS epack = 32KB)
#define SCH 4096  // entries per block in device-wide scan (256 thr x 16)

typedef float floatx2 __attribute__((ext_vector_type(2)));
typedef float f32x4 __attribute__((ext_vector_type(4)));
typedef short short8v __attribute__((ext_vector_type(8)));

union ABfrag { short8v s; unsigned int u[4]; };

__device__ __forceinline__ unsigned int f2bf_pair(float f0, float f1) {
    unsigned int u0 = __float_as_uint(f0);
    unsigned int u1 = __float_as_uint(f1);
    u0 = (u0 + 0x7FFFu + ((u0 >> 16) & 1u)) >> 16;   // RNE
    u1 = (u1 + 0x7FFFu + ((u1 >> 16) & 1u)) >> 16;
    return u0 | (u1 << 16);
}
__device__ __forceinline__ float bf_lo(unsigned int p) { return __uint_as_float(p << 16); }
__device__ __forceinline__ float bf_hi(unsigned int p) { return __uint_as_float(p & 0xFFFF0000u); }

__device__ __forceinline__ unsigned int pack4_fp8(float f0, float f1, float f2, float f3) {
    int r = 0;
    r = __builtin_amdgcn_cvt_pk_fp8_f32(f0, f1, r, false);
    r = __builtin_amdgcn_cvt_pk_fp8_f32(f2, f3, r, true);
    return (unsigned int)r;
}

// ---------------- bucketed CSR build (no global atomics) ----------------
__global__ void histA_kernel(const int* __restrict__ ei, int E, int NB, int NC,
                             int* __restrict__ blockHist) {
    __shared__ int hist[512];
    int c = blockIdx.x;
    int tid = threadIdx.x;
    for (int i = tid; i < 512; i += 256) hist[i] = 0;
    __syncthreads();
    int beg = c * CH, end = min(E, beg + CH);
    for (int i = beg + tid; i < end; i += 256) {
        int d = ei[(size_t)E + i];
        atomicAdd(&hist[d >> BSH], 1);
    }
    __syncthreads();
    for (int i = tid; i < NB; i += 256) blockHist[i * NC + c] = hist[i];   // bucket-major
}

// ---- device-wide exclusive scan of blockHist ----
__global__ void scan1_kernel(const int* __restrict__ bh, int M, int* __restrict__ csum) {
    __shared__ int red[4];
    int tid = threadIdx.x;
    int lane = tid & 63, wv = tid >> 6;
    int base = blockIdx.x * SCH + tid * 16;
    int s = 0;
    if (base + 16 <= M) {
#pragma unroll
        for (int j = 0; j < 4; j++) {
            int4 v = *(const int4*)(bh + base + 4 * j);
            s += v.x + v.y + v.z + v.w;
        }
    } else {
        for (int j = 0; j < 16 && base + j < M; j++) s += bh[base + j];
    }
    for (int off = 1; off < 64; off <<= 1) s += __shfl_xor(s, off);
    if (lane == 0) red[wv] = s;
    __syncthreads();
    if (tid == 0) csum[blockIdx.x] = red[0] + red[1] + red[2] + red[3];
}

__global__ void scan2_kernel(int* __restrict__ csum, int nb,
                             int* __restrict__ rowptr, int N, int E) {
    int lane = threadIdx.x;    // one wave, nb <= 64
    int v = (lane < nb) ? csum[lane] : 0;
    int orig = v;
    for (int off = 1; off < 64; off <<= 1) {
        int u = __shfl_up(v, off);
        if (lane >= off) v += u;
    }
    if (lane < nb) csum[lane] = v - orig;   // exclusive base per chunk
    if (lane == 0) rowptr[N] = E;
}

__global__ void scan3_kernel(const int* __restrict__ bh, int M, const int* __restrict__ csum,
                             int* __restrict__ scanned) {
    __shared__ int wsum[4];
    int tid = threadIdx.x;
    int lane = tid & 63, wv = tid >> 6;
    int base = blockIdx.x * SCH + tid * 16;
    int a[16];
#pragma unroll
    for (int j = 0; j < 16; j++) a[j] = 0;
    if (base + 16 <= M) {
#pragma unroll
        for (int j = 0; j < 4; j++) {
            int4 v = *(const int4*)(bh + base + 4 * j);
            a[4 * j] = v.x; a[4 * j + 1] = v.y; a[4 * j + 2] = v.z; a[4 * j + 3] = v.w;
        }
    } else {
        for (int j = 0; j < 16 && base + j < M; j++) a[j] = bh[base + j];
    }
    int t = 0;
#pragma unroll
    for (int j = 0; j < 16; j++) t += a[j];
    int inc = t;
    for (int off = 1; off < 64; off <<= 1) {
        int u = __shfl_up(inc, off);
        if (lane >= off) inc += u;
    }
    if (lane == 63) wsum[wv] = inc;
    __syncthreads();
    int wb = 0;
    for (int w = 0; w < wv; w++) wb += wsum[w];
    int run = csum[blockIdx.x] + wb + (inc - t);
    if (base + 16 <= M) {
#pragma unroll
        for (int j = 0; j < 4; j++) {
            int4 o;
            o.x = run; run += a[4 * j];
            o.y = run; run += a[4 * j + 1];
            o.z = run; run += a[4 * j + 2];
            o.w = run; run += a[4 * j + 3];
            *(int4*)(scanned + base + 4 * j) = o;
        }
    } else {
        for (int j = 0; j < 16 && base + j < M; j++) { scanned[base + j] = run; run += a[j]; }
    }
}

// ---- scatter: LDS-sort chunk by bucket, then fully-coalesced ordered copy-out ----
__global__ void scatterB_kernel(const int* __restrict__ ei, int E, int NB, int NC,
                                const int* __restrict__ blockHist,
                                const int* __restrict__ scanned, int* __restrict__ ebuf) {
    __shared__ int part[512];
    __shared__ int lofs[512];
    __shared__ int gofs[512];
    __shared__ int cur[512];
    __shared__ int epack[CH];
    int c = blockIdx.x;
    int tid = threadIdx.x;        // 512 threads
    int v = (tid < NB) ? blockHist[tid * NC + c] : 0;
    part[tid] = v;
    __syncthreads();
    for (int off = 1; off < 512; off <<= 1) {
        int u = (tid >= off) ? part[tid - off] : 0;
        __syncthreads();
        part[tid] += u;
        __syncthreads();
    }
    int ex = (tid == 0) ? 0 : part[tid - 1];
    lofs[tid] = ex;
    cur[tid] = ex;
    if (tid < NB) gofs[tid] = scanned[tid * NC + c];
    __syncthreads();
    int beg = c * CH, end = min(E, beg + CH), len = end - beg;
    for (int i = beg + tid; i < end; i += 512) {
        int s = ei[i];
        int d = ei[(size_t)E + i];
        int b = d >> BSH;
        int pos = atomicAdd(&cur[b], 1);
        epack[pos] = ((d & (BSZ - 1)) << 17) | s;
    }
    __syncthreads();
    for (int j = tid; j < len; j += 512) {
        int lo = 0, hi = NB - 1;
        while (lo < hi) { int mid = (lo + hi + 1) >> 1; if (lofs[mid] <= j) lo = mid; else hi = mid - 1; }
        ebuf[gofs[lo] + (j - lofs[lo])] = epack[j];
    }
}

__global__ void buildC_kernel(const int* __restrict__ ebuf, const int* __restrict__ scanned,
                              int NB, int NC, int N, int E,
                              int* __restrict__ rowptr, float* __restrict__ dinv,
                              int* __restrict__ colidx) {
    __shared__ int cnt[BSZ], woff[BSZ], part[BSZ];
    int b = blockIdx.x;
    int tid = threadIdx.x;
    int ebeg = scanned[b * NC];
    int eend = (b == NB - 1) ? E : scanned[(b + 1) * NC];
    if (tid < BSZ) cnt[tid] = 0;
    __syncthreads();
    for (int i = ebeg + tid; i < eend; i += 512) {
        atomicAdd(&cnt[ebuf[i] >> 17], 1);
    }
    __syncthreads();
    if (tid < BSZ) part[tid] = cnt[tid];
    __syncthreads();
    for (int off = 1; off < BSZ; off <<= 1) {
        int v = 0;
        if (tid < BSZ && tid >= off) v = part[tid - off];
        __syncthreads();
        if (tid < BSZ) part[tid] += v;
        __syncthreads();
    }
    if (tid < BSZ) {
        int ex = (tid == 0) ? 0 : part[tid - 1];
        woff[tid] = ex;
        int node = (b << BSH) + tid;
        if (node < N) {
            rowptr[node] = ebeg + ex;
            dinv[node] = 1.0f / sqrtf((float)(cnt[tid] + 1));   // +1 self loop
        }
    }
    __syncthreads();
    for (int i = ebeg + tid; i < eend; i += 512) {
        int p = ebuf[i];
        int dl = p >> 17;
        int s = p & 0x1FFFF;
        int pos = atomicAdd(&woff[dl], 1);
        colidx[ebeg + pos] = s;
    }
}

// ---------------- MFMA GEMM layer 1: x fp32 [N][136] @ W1 -> fp8 half rows ----------------
// Block: 256 thr = 4 waves; wave w: rows [blk*64 + w*16, +16) x 64 cols.
// x staged coalesced into xls bf16 per 32-k step; A-frag via ds_read_b128.
// Epilogue fp32 tile overlays wsT (LDS 26.6 KB total -> 6 blocks/CU).
__global__ void gemm1_mfma(const float* __restrict__ x, int K, int H,
                           const float* __restrict__ W,
                           const float* __restrict__ dinv,
                           unsigned int* __restrict__ hsA,
                           unsigned int* __restrict__ hsB, int N) {
    const int KP = 160, S = 168, LSS = 68;
    __shared__ unsigned short wsT[64 * S];      // 21504 B; overlaid by ls after K-loop
    __shared__ unsigned short xls[64][40];      // 5120 B (pad 40: 2-way banks, free)
    float (*ls)[16][LSS] = (float (*)[16][LSS])wsT;   // 4*16*68*4 = 17408 B overlay
    int tid = threadIdx.x;
    int w = tid >> 6, lane = tid & 63;
    int row0 = blockIdx.x * 64;
    // stage W transposed (coalesced read, LDS scatter write)
    for (int i = tid; i < KP * 64; i += 256) {
        int k = i >> 6, col = i & 63;
        float v = (k < K && col < H) ? W[k * H + col] : 0.0f;
        wsT[col * S + k] = (unsigned short)(f2bf_pair(v, 0.0f) & 0xFFFFu);
    }
    __syncthreads();

    int lrow = w * 16 + (lane & 15);
    int kgrp = (lane >> 4) * 8;
    f32x4 acc0 = 0.0f, acc1 = 0.0f, acc2 = 0.0f, acc3 = 0.0f;
    for (int k0 = 0; k0 < KP; k0 += 32) {
        // stage 64 rows x 32 k of x as bf16 (coalesced: 8 threads per row, 16B each)
        for (int i = tid; i < 512; i += 256) {
            int rl = i >> 3, seg = i & 7;
            int gr = row0 + rl, gk = k0 + seg * 4;
            uint2 pk = make_uint2(0u, 0u);
            if (gr < N && gk < K) {               // K%4==0: gk<K => gk+4<=K
                float4 v = *(const float4*)(x + (size_t)gr * K + gk);
                pk.x = f2bf_pair(v.x, v.y);
                pk.y = f2bf_pair(v.z, v.w);
            }
            *(uint2*)&xls[rl][seg * 4] = pk;
        }
        __syncthreads();
        ABfrag a;
        a.s = *(const short8v*)&xls[lrow][kgrp];
        int koff = k0 + kgrp;
        ABfrag b0, b1, b2, b3;
        b0.s = *(const short8v*)&wsT[(0 * 16 + (lane & 15)) * S + koff];
        b1.s = *(const short8v*)&wsT[(1 * 16 + (lane & 15)) * S + koff];
        b2.s = *(const short8v*)&wsT[(2 * 16 + (lane & 15)) * S + koff];
        b3.s = *(const short8v*)&wsT[(3 * 16 + (lane & 15)) * S + koff];
        acc0 = __builtin_amdgcn_mfma_f32_16x16x32_bf16(a.s, b0.s, acc0, 0, 0, 0);
        acc1 = __builtin_amdgcn_mfma_f32_16x16x32_bf16(a.s, b1.s, acc1, 0, 0, 0);
        acc2 = __builtin_amdgcn_mfma_f32_16x16x32_bf16(a.s, b2.s, acc2, 0, 0, 0);
        acc3 = __builtin_amdgcn_mfma_f32_16x16x32_bf16(a.s, b3.s, acc3, 0, 0, 0);
        __syncthreads();
    }
    // epilogue: C layout col = lane&15, row = (lane>>4)*4 + reg (overlay onto wsT)
    int r4 = (lane >> 4) * 4;
#pragma unroll
    for (int r = 0; r < 4; r++) {
        ls[w][r4 + r][0 * 16 + (lane & 15)] = acc0[r];
        ls[w][r4 + r][1 * 16 + (lane & 15)] = acc1[r];
        ls[w][r4 + r][2 * 16 + (lane & 15)] = acc2[r];
        ls[w][r4 + r][3 * 16 + (lane & 15)] = acc3[r];
    }
    __syncthreads();
    int prow = lane >> 2, cg = lane & 3;
    int row = row0 + w * 16 + prow;
    if (row < N) {
        float dv = dinv[row];
        const float* lr = &ls[w][prow][cg * 16];
        uint4 o;
        o.x = pack4_fp8(lr[0] * dv, lr[1] * dv, lr[2] * dv, lr[3] * dv);
        o.y = pack4_fp8(lr[4] * dv, lr[5] * dv, lr[6] * dv, lr[7] * dv);
        o.z = pack4_fp8(lr[8] * dv, lr[9] * dv, lr[10] * dv, lr[11] * dv);
        o.w = pack4_fp8(lr[12] * dv, lr[13] * dv, lr[14] * dv, lr[15] * dv);
        if (cg < 2) ((uint4*)(hsA + (size_t)row * 8))[cg] = o;
        else        ((uint4*)(hsB + (size_t)row * 8))[cg - 2] = o;
    }
}

// ---------------- MFMA GEMM layer 2: buf bf16 [N][64] @ W2 -> fp8 half rows ----------------
__global__ void gemm2_mfma(const unsigned int* __restrict__ in, int K, int H,
                           const float* __restrict__ W,
                           const float* __restrict__ dinv,
                           unsigned int* __restrict__ hsA,
                           unsigned int* __restrict__ hsB, int N) {
    const int KP = 64, S = 72;
    __shared__ unsigned short wsT[64 * S];   // 9216 B
    __shared__ float ls[4][16][64];
    int tid = threadIdx.x;
    int w = tid >> 6, lane = tid & 63;
    int row0 = blockIdx.x * 64 + w * 16;
    for (int i = tid; i < KP * 64; i += 256) {
        int k = i >> 6, col = i & 63;
        float v = (k < K && col < H) ? W[k * H + col] : 0.0f;
        wsT[col * S + k] = (unsigned short)(f2bf_pair(v, 0.0f) & 0xFFFFu);
    }
    __syncthreads();

    int arow = row0 + (lane & 15);
    int kgrp = (lane >> 4) * 8;
    f32x4 acc0 = 0.0f, acc1 = 0.0f, acc2 = 0.0f, acc3 = 0.0f;
    for (int k0 = 0; k0 < KP; k0 += 32) {
        int koff = k0 + kgrp;
        ABfrag a; a.u[0] = 0; a.u[1] = 0; a.u[2] = 0; a.u[3] = 0;
        if (arow < N) {
            uint4 v = *(const uint4*)(in + (size_t)arow * 32 + (koff >> 1));  // 8 bf16
            a.u[0] = v.x; a.u[1] = v.y; a.u[2] = v.z; a.u[3] = v.w;
        }
        ABfrag b0, b1, b2, b3;
        b0.s = *(const short8v*)&wsT[(0 * 16 + (lane & 15)) * S + koff];
        b1.s = *(const short8v*)&wsT[(1 * 16 + (lane & 15)) * S + koff];
        b2.s = *(const short8v*)&wsT[(2 * 16 + (lane & 15)) * S + koff];
        b3.s = *(const short8v*)&wsT[(3 * 16 + (lane & 15)) * S + koff];
        acc0 = __builtin_amdgcn_mfma_f32_16x16x32_bf16(a.s, b0.s, acc0, 0, 0, 0);
        acc1 = __builtin_amdgcn_mfma_f32_16x16x32_bf16(a.s, b1.s, acc1, 0, 0, 0);
        acc2 = __builtin_amdgcn_mfma_f32_16x16x32_bf16(a.s, b2.s, acc2, 0, 0, 0);
        acc3 = __builtin_amdgcn_mfma_f32_16x16x32_bf16(a.s, b3.s, acc3, 0, 0, 0);
    }
    int r4 = (lane >> 4) * 4;
#pragma unroll
    for (int r = 0; r < 4; r++) {
        ls[w][r4 + r][0 * 16 + (lane & 15)] = acc0[r];
        ls[w][r4 + r][1 * 16 + (lane & 15)] = acc1[r];
        ls[w][r4 + r][2 * 16 + (lane & 15)] = acc2[r];
        ls[w][r4 + r][3 * 16 + (lane & 15)] = acc3[r];
    }
    __syncthreads();
    int prow = lane >> 2, cg = lane & 3;
    int row = row0 + prow;
    if (row < N) {
        float dv = dinv[row];
        const float* lr = &ls[w][prow][cg * 16];
        uint4 o;
        o.x = pack4_fp8(lr[0] * dv, lr[1] * dv, lr[2] * dv, lr[3] * dv);
        o.y = pack4_fp8(lr[4] * dv, lr[5] * dv, lr[6] * dv, lr[7] * dv);
        o.z = pack4_fp8(lr[8] * dv, lr[9] * dv, lr[10] * dv, lr[11] * dv);
        o.w = pack4_fp8(lr[12] * dv, lr[13] * dv, lr[14] * dv, lr[15] * dv);
        if (cg < 2) ((uint4*)(hsA + (size_t)row * 8))[cg] = o;
        else        ((uint4*)(hsB + (size_t)row * 8))[cg - 2] = o;
    }
}

// ---------------- aggregation over one fp8 half (32B rows, L2-resident) ----------------
__global__ void agg_half_kernel(const unsigned int* __restrict__ hsh,
                                const int* __restrict__ rowptr, const int* __restrict__ colidx,
                                const float* __restrict__ dinv, const float* __restrict__ bias,
                                int cbase, unsigned int* __restrict__ outbuf, int N) {
    int t = blockIdx.x * blockDim.x + threadIdx.x;
    int node = t >> 3;
    int q = t & 7;
    if (node >= N) return;
    const unsigned int* basq = hsh + q;
    unsigned int sv = basq[(size_t)node * 8];   // self loop term
    floatx2 plo = __builtin_amdgcn_cvt_pk_f32_fp8((int)sv, false);
    floatx2 phi = __builtin_amdgcn_cvt_pk_f32_fp8((int)sv, true);
    float a0 = plo[0], a1 = plo[1], a2 = phi[0], a3 = phi[1];
    int beg = rowptr[node], end = rowptr[node + 1];
    int e = beg;
    for (; e + 4 <= end; e += 4) {
        int s0 = colidx[e], s1 = colidx[e + 1], s2 = colidx[e + 2], s3 = colidx[e + 3];
        unsigned int v0 = basq[(size_t)s0 * 8];
        unsigned int v1 = basq[(size_t)s1 * 8];
        unsigned int v2 = basq[(size_t)s2 * 8];
        unsigned int v3 = basq[(size_t)s3 * 8];
        floatx2 l0 = __builtin_amdgcn_cvt_pk_f32_fp8((int)v0, false);
        floatx2 h0 = __builtin_amdgcn_cvt_pk_f32_fp8((int)v0, true);
        floatx2 l1 = __builtin_amdgcn_cvt_pk_f32_fp8((int)v1, false);
        floatx2 h1 = __builtin_amdgcn_cvt_pk_f32_fp8((int)v1, true);
        floatx2 l2 = __builtin_amdgcn_cvt_pk_f32_fp8((int)v2, false);
        floatx2 h2 = __builtin_amdgcn_cvt_pk_f32_fp8((int)v2, true);
        floatx2 l3 = __builtin_amdgcn_cvt_pk_f32_fp8((int)v3, false);
        floatx2 h3 = __builtin_amdgcn_cvt_pk_f32_fp8((int)v3, true);
        a0 += (l0[0] + l1[0]) + (l2[0] + l3[0]);
        a1 += (l0[1] + l1[1]) + (l2[1] + l3[1]);
        a2 += (h0[0] + h1[0]) + (h2[0] + h3[0]);
        a3 += (h0[1] + h1[1]) + (h2[1] + h3[1]);
    }
    for (; e < end; e++) {
        int s0 = colidx[e];
        unsigned int v0 = basq[(size_t)s0 * 8];
        floatx2 l0 = __builtin_amdgcn_cvt_pk_f32_fp8((int)v0, false);
        floatx2 h0 = __builtin_amdgcn_cvt_pk_f32_fp8((int)v0, true);
        a0 += l0[0]; a1 += l0[1]; a2 += h0[0]; a3 += h0[1];
    }
    float dv = dinv[node];
    int c0 = cbase + q * 4;
    float b0 = (c0 + 0 < HH) ? bias[c0 + 0] : 0.0f;
    float b1 = (c0 + 1 < HH) ? bias[c0 + 1] : 0.0f;
    float b2 = (c0 + 2 < HH) ? bias[c0 + 2] : 0.0f;
    float b3 = (c0 + 3 < HH) ? bias[c0 + 3] : 0.0f;
    float r0 = fmaxf(a0 * dv + b0, 0.0f);
    float r1 = fmaxf(a1 * dv + b1, 0.0f);
    float r2 = fmaxf(a2 * dv + b2, 0.0f);
    float r3 = fmaxf(a3 * dv + b3, 0.0f);
    uint2 w;
    if (c0 >= HH) { w.x = 0u; w.y = 0u; }
    else { w.x = f2bf_pair(r0, r1); w.y = f2bf_pair(r2, r3); }
    ((uint2*)outbuf)[(size_t)node * 16 + (cbase >> 2) + q] = w;
}

// ---------------- pooling + head over bf16 rows (bounds searched inline) ----------------
__global__ void pool_head_kernel(const unsigned int* __restrict__ h,
                                 const int* __restrict__ batch, int N,
                                 const float* __restrict__ Wl, const float* __restrict__ bl,
                                 float* __restrict__ out, int G) {
    __shared__ float4 red[16][16];    // [sub][q]
    int b = blockIdx.x;
    int t = threadIdx.x;
    int sub = t >> 4, q = t & 15;
    int beg, end;
    {
        int lo = 0, hi = N;
        while (lo < hi) { int mid = (lo + hi) >> 1; if (batch[mid] < b) lo = mid + 1; else hi = mid; }
        beg = lo;
        lo = 0; hi = N;
        while (lo < hi) { int mid = (lo + hi) >> 1; if (batch[mid] < b + 1) lo = mid + 1; else hi = mid; }
        end = lo;
    }
    const uint2* base = (const uint2*)h;
    float4 acc = make_float4(0.f, 0.f, 0.f, 0.f);
    for (int node = beg + sub; node < end; node += 16) {
        uint2 v = base[(size_t)node * 16 + q];
        acc.x += bf_lo(v.x); acc.y += bf_hi(v.x); acc.z += bf_lo(v.y); acc.w += bf_hi(v.y);
    }
    red[sub][q] = acc;
    __syncthreads();
#pragma unroll
    for (int off = 8; off >= 1; off >>= 1) {
        if (sub < off) {
            float4 a = red[sub][q], c = red[sub + off][q];
            a.x += c.x; a.y += c.y; a.z += c.z; a.w += c.w;
            red[sub][q] = a;
        }
        __syncthreads();
    }
    if (t == 0) {
        const float* g = (const float*)&red[0][0];
        float dot = 0.0f;
        for (int c = 0; c < HH; c++) dot += g[c] * Wl[c];
        float cnt = (float)(end - beg);
        float x = dot / fmaxf(cnt, 1.0f) + bl[0];
        out[b] = 1.0f / (1.0f + expf(-x));
    }
}

extern "C" void kernel_launch(void* const* d_in, const int* in_sizes, int n_in,
                              void* d_out, int out_size, void* d_ws, size_t ws_size,
                              hipStream_t stream) {
    const float* x     = (const float*)d_in[0];
    const int*   ei    = (const int*)d_in[1];
    const int*   batch = (const int*)d_in[2];
    const float* W1    = (const float*)d_in[3];
    const float* b1    = (const float*)d_in[4];
    const float* W2    = (const float*)d_in[5];
    const float* b2    = (const float*)d_in[6];
    const float* Wl    = (const float*)d_in[7];
    const float* bl    = (const float*)d_in[8];
    float* out = (float*)d_out;

    int N = in_sizes[2];
    int E = in_sizes[1] / 2;
    int F = in_sizes[0] / N;       // 136
    int G = out_size;              // 256 graphs

    int NB = (N + BSZ - 1) >> BSH;    // ~391 buckets
    int NC = (E + CH - 1) / CH;       // ~391 chunks
    int M  = NB * NC;
    int NS = (M + SCH - 1) / SCH;     // <=64 for this size

    char* ws = (char*)d_ws;
    size_t off = 0;
    auto alloc = [&](size_t bytes) -> void* {
        void* p = ws + off;
        off += (bytes + 255) & ~(size_t)255;
        return p;
    };
    size_t halfBytes = (size_t)N * 32;       // fp8 half rows (32B)
    size_t bufBytes  = (size_t)N * 128;      // bf16 rows (128B)
    size_t ebufBytes = (size_t)E * 4;
    float*        dinv      = (float*)alloc((size_t)N * 4);
    int*          rowptr    = (int*)alloc((size_t)(N + 1) * 4);
    int*          colidx    = (int*)alloc(ebufBytes);
    unsigned int* hsA       = (unsigned int*)alloc(halfBytes);
    unsigned int* hsB       = (unsigned int*)alloc(halfBytes);
    unsigned int* buf       = (unsigned int*)alloc(bufBytes > ebufBytes ? bufBytes : ebufBytes);
    int*          blockHist = (int*)alloc((size_t)M * 4);
    int*          scanned   = (int*)alloc((size_t)M * 4);
    int*          csum      = (int*)alloc((size_t)NS * 4 + 256);
    int*          ebuf      = (int*)buf;    // alias: dead before first agg writes buf

    // CSR build (by dst), no global atomics
    histA_kernel<<<NC, 256, 0, stream>>>(ei, E, NB, NC, blockHist);
    scan1_kernel<<<NS, 256, 0, stream>>>(blockHist, M, csum);
    scan2_kernel<<<1, 64, 0, stream>>>(csum, NS, rowptr, N, E);
    scan3_kernel<<<NS, 256, 0, stream>>>(blockHist, M, csum, scanned);
    scatterB_kernel<<<NC, 512, 0, stream>>>(ei, E, NB, NC, blockHist, scanned, ebuf);
    buildC_kernel<<<NB, 512, 0, stream>>>(ebuf, scanned, NB, NC, N, E, rowptr, dinv, colidx);

    int aggBlocks = ((N * 8) + 255) / 256;
    int mfmaBlocks = (N + 63) / 64;

    // layer 1
    gemm1_mfma<<<mfmaBlocks, 256, 0, stream>>>(x, F, HH, W1, dinv, hsA, hsB, N);
    agg_half_kernel<<<aggBlocks, 256, 0, stream>>>(hsA, rowptr, colidx, dinv, b1, 0,  buf, N);
    agg_half_kernel<<<aggBlocks, 256, 0, stream>>>(hsB, rowptr, colidx, dinv, b1, 32, buf, N);

    // layer 2
    gemm2_mfma<<<mfmaBlocks, 256, 0, stream>>>(buf, HH, HH, W2, dinv, hsA, hsB, N);
    agg_half_kernel<<<aggBlocks, 256, 0, stream>>>(hsA, rowptr, colidx, dinv, b2, 0,  buf, N);
    agg_half_kernel<<<aggBlocks, 256, 0, stream>>>(hsB, rowptr, colidx, dinv, b2, 32, buf, N);

    // pooling + fused head
    pool_head_kernel<<<G, 256, 0, stream>>>(buf, batch, N, Wl, bl, out, G);
}

// Round 18
// 231.189 us; speedup vs baseline: 1.0860x; 1.0860x over previous
//
#include <hip/hip_runtime.h>
#include <math.h>

#define HH 50     // hidden features
#define BSH 8     // bucket shift: 256 nodes per bucket
#define BSZ 256
#define CH 8192   // edges per chunk in bucketed CSR build (LDS epack = 32KB)
#define SCH 4096  // entries per block in device-wide scan (256 thr x 16)

typedef float floatx2 __attribute__((ext_vector_type(2)));
typedef float f32x4 __attribute__((ext_vector_type(4)));
typedef short short8v __attribute__((ext_vector_type(8)));

union ABfrag { short8v s; unsigned int u[4]; };

__device__ __forceinline__ unsigned int f2bf_pair(float f0, float f1) {
    unsigned int u0 = __float_as_uint(f0);
    unsigned int u1 = __float_as_uint(f1);
    u0 = (u0 + 0x7FFFu + ((u0 >> 16) & 1u)) >> 16;   // RNE
    u1 = (u1 + 0x7FFFu + ((u1 >> 16) & 1u)) >> 16;
    return u0 | (u1 << 16);
}
__device__ __forceinline__ float bf_lo(unsigned int p) { return __uint_as_float(p << 16); }
__device__ __forceinline__ float bf_hi(unsigned int p) { return __uint_as_float(p & 0xFFFF0000u); }

__device__ __forceinline__ unsigned int pack4_fp8(float f0, float f1, float f2, float f3) {
    int r = 0;
    r = __builtin_amdgcn_cvt_pk_fp8_f32(f0, f1, r, false);
    r = __builtin_amdgcn_cvt_pk_fp8_f32(f2, f3, r, true);
    return (unsigned int)r;
}

// ---------------- bucketed CSR build (no global atomics) ----------------
__global__ void histA_kernel(const int* __restrict__ ei, int E, int NB, int NC,
                             int* __restrict__ blockHist) {
    __shared__ int hist[512];
    int c = blockIdx.x;
    int tid = threadIdx.x;
    for (int i = tid; i < 512; i += 256) hist[i] = 0;
    __syncthreads();
    int beg = c * CH, end = min(E, beg + CH);
    for (int i = beg + tid; i < end; i += 256) {
        int d = ei[(size_t)E + i];
        atomicAdd(&hist[d >> BSH], 1);
    }
    __syncthreads();
    for (int i = tid; i < NB; i += 256) blockHist[i * NC + c] = hist[i];   // bucket-major
}

// ---- device-wide exclusive scan of blockHist ----
__global__ void scan1_kernel(const int* __restrict__ bh, int M, int* __restrict__ csum) {
    __shared__ int red[4];
    int tid = threadIdx.x;
    int lane = tid & 63, wv = tid >> 6;
    int base = blockIdx.x * SCH + tid * 16;
    int s = 0;
    if (base + 16 <= M) {
#pragma unroll
        for (int j = 0; j < 4; j++) {
            int4 v = *(const int4*)(bh + base + 4 * j);
            s += v.x + v.y + v.z + v.w;
        }
    } else {
        for (int j = 0; j < 16 && base + j < M; j++) s += bh[base + j];
    }
    for (int off = 1; off < 64; off <<= 1) s += __shfl_xor(s, off);
    if (lane == 0) red[wv] = s;
    __syncthreads();
    if (tid == 0) csum[blockIdx.x] = red[0] + red[1] + red[2] + red[3];
}

__global__ void scan2_kernel(int* __restrict__ csum, int nb,
                             int* __restrict__ rowptr, int N, int E) {
    int lane = threadIdx.x;    // one wave, nb <= 64
    int v = (lane < nb) ? csum[lane] : 0;
    int orig = v;
    for (int off = 1; off < 64; off <<= 1) {
        int u = __shfl_up(v, off);
        if (lane >= off) v += u;
    }
    if (lane < nb) csum[lane] = v - orig;   // exclusive base per chunk
    if (lane == 0) rowptr[N] = E;
}

__global__ void scan3_kernel(const int* __restrict__ bh, int M, const int* __restrict__ csum,
                             int* __restrict__ scanned) {
    __shared__ int wsum[4];
    int tid = threadIdx.x;
    int lane = tid & 63, wv = tid >> 6;
    int base = blockIdx.x * SCH + tid * 16;
    int a[16];
#pragma unroll
    for (int j = 0; j < 16; j++) a[j] = 0;
    if (base + 16 <= M) {
#pragma unroll
        for (int j = 0; j < 4; j++) {
            int4 v = *(const int4*)(bh + base + 4 * j);
            a[4 * j] = v.x; a[4 * j + 1] = v.y; a[4 * j + 2] = v.z; a[4 * j + 3] = v.w;
        }
    } else {
        for (int j = 0; j < 16 && base + j < M; j++) a[j] = bh[base + j];
    }
    int t = 0;
#pragma unroll
    for (int j = 0; j < 16; j++) t += a[j];
    int inc = t;
    for (int off = 1; off < 64; off <<= 1) {
        int u = __shfl_up(inc, off);
        if (lane >= off) inc += u;
    }
    if (lane == 63) wsum[wv] = inc;
    __syncthreads();
    int wb = 0;
    for (int w = 0; w < wv; w++) wb += wsum[w];
    int run = csum[blockIdx.x] + wb + (inc - t);
    if (base + 16 <= M) {
#pragma unroll
        for (int j = 0; j < 4; j++) {
            int4 o;
            o.x = run; run += a[4 * j];
            o.y = run; run += a[4 * j + 1];
            o.z = run; run += a[4 * j + 2];
            o.w = run; run += a[4 * j + 3];
            *(int4*)(scanned + base + 4 * j) = o;
        }
    } else {
        for (int j = 0; j < 16 && base + j < M; j++) { scanned[base + j] = run; run += a[j]; }
    }
}

// ---- scatter: LDS-sort chunk by bucket, then fully-coalesced ordered copy-out ----
__global__ void scatterB_kernel(const int* __restrict__ ei, int E, int NB, int NC,
                                const int* __restrict__ blockHist,
                                const int* __restrict__ scanned, int* __restrict__ ebuf) {
    __shared__ int part[512];
    __shared__ int lofs[512];
    __shared__ int gofs[512];
    __shared__ int cur[512];
    __shared__ int epack[CH];
    int c = blockIdx.x;
    int tid = threadIdx.x;        // 512 threads
    int v = (tid < NB) ? blockHist[tid * NC + c] : 0;
    part[tid] = v;
    __syncthreads();
    for (int off = 1; off < 512; off <<= 1) {
        int u = (tid >= off) ? part[tid - off] : 0;
        __syncthreads();
        part[tid] += u;
        __syncthreads();
    }
    int ex = (tid == 0) ? 0 : part[tid - 1];
    lofs[tid] = ex;
    cur[tid] = ex;
    if (tid < NB) gofs[tid] = scanned[tid * NC + c];
    __syncthreads();
    int beg = c * CH, end = min(E, beg + CH), len = end - beg;
    for (int i = beg + tid; i < end; i += 512) {
        int s = ei[i];
        int d = ei[(size_t)E + i];
        int b = d >> BSH;
        int pos = atomicAdd(&cur[b], 1);
        epack[pos] = ((d & (BSZ - 1)) << 17) | s;
    }
    __syncthreads();
    for (int j = tid; j < len; j += 512) {
        int lo = 0, hi = NB - 1;
        while (lo < hi) { int mid = (lo + hi + 1) >> 1; if (lofs[mid] <= j) lo = mid; else hi = mid - 1; }
        ebuf[gofs[lo] + (j - lofs[lo])] = epack[j];
    }
}

__global__ void buildC_kernel(const int* __restrict__ ebuf, const int* __restrict__ scanned,
                              int NB, int NC, int N, int E,
                              int* __restrict__ rowptr, float* __restrict__ dinv,
                              int* __restrict__ colidx) {
    __shared__ int cnt[BSZ], woff[BSZ], part[BSZ];
    int b = blockIdx.x;
    int tid = threadIdx.x;
    int ebeg = scanned[b * NC];
    int eend = (b == NB - 1) ? E : scanned[(b + 1) * NC];
    if (tid < BSZ) cnt[tid] = 0;
    __syncthreads();
    for (int i = ebeg + tid; i < eend; i += 512) {
        atomicAdd(&cnt[ebuf[i] >> 17], 1);
    }
    __syncthreads();
    if (tid < BSZ) part[tid] = cnt[tid];
    __syncthreads();
    for (int off = 1; off < BSZ; off <<= 1) {
        int v = 0;
        if (tid < BSZ && tid >= off) v = part[tid - off];
        __syncthreads();
        if (tid < BSZ) part[tid] += v;
        __syncthreads();
    }
    if (tid < BSZ) {
        int ex = (tid == 0) ? 0 : part[tid - 1];
        woff[tid] = ex;
        int node = (b << BSH) + tid;
        if (node < N) {
            rowptr[node] = ebeg + ex;
            dinv[node] = 1.0f / sqrtf((float)(cnt[tid] + 1));   // +1 self loop
        }
    }
    __syncthreads();
    for (int i = ebeg + tid; i < eend; i += 512) {
        int p = ebuf[i];
        int dl = p >> 17;
        int s = p & 0x1FFFF;
        int pos = atomicAdd(&woff[dl], 1);
        colidx[ebeg + pos] = s;
    }
}

// ---------------- one-time W transpose to bf16 global (L2-resident) ----------------
// w1t[col][k]: 64 x 168 shorts; w2t[col][k]: 64 x 72 shorts.
__global__ void prepW_kernel(const float* __restrict__ W1, int K1, int H,
                             const float* __restrict__ W2, int K2,
                             unsigned short* __restrict__ w1t,
                             unsigned short* __restrict__ w2t) {
    int i = blockIdx.x * 256 + threadIdx.x;
    if (i < 64 * 168) {
        int col = i / 168, k = i % 168;
        float v = (k < K1 && col < H) ? W1[k * H + col] : 0.0f;
        w1t[col * 168 + k] = (unsigned short)(f2bf_pair(v, 0.0f) & 0xFFFFu);
    }
    if (i < 64 * 72) {
        int col = i / 72, k = i % 72;
        float v = (k < K2 && col < H) ? W2[k * H + col] : 0.0f;
        w2t[col * 72 + k] = (unsigned short)(f2bf_pair(v, 0.0f) & 0xFFFFu);
    }
}

// ---------------- MFMA GEMM layer 1: x fp32 [N][136] @ W1 -> fp8 half rows ----------------
// B-frags straight from global w1t (L2-hit). LDS = union{xls during K-loop, ls epilogue}.
__global__ void gemm1_mfma(const float* __restrict__ x, int K, int H,
                           const unsigned short* __restrict__ w1t,
                           const float* __restrict__ dinv,
                           unsigned int* __restrict__ hsA,
                           unsigned int* __restrict__ hsB, int N) {
    const int KP = 160, LSS = 68;
    __shared__ __align__(16) char smem[4 * 16 * LSS * 4];   // 17408 B
    unsigned short (*xls)[40] = (unsigned short (*)[40])smem;     // 5120 B overlay
    float (*ls)[16][LSS] = (float (*)[16][LSS])smem;              // epilogue overlay
    int tid = threadIdx.x;
    int w = tid >> 6, lane = tid & 63;
    int row0 = blockIdx.x * 64;

    int lrow = w * 16 + (lane & 15);
    int kgrp = (lane >> 4) * 8;
    f32x4 acc0 = 0.0f, acc1 = 0.0f, acc2 = 0.0f, acc3 = 0.0f;
#pragma unroll
    for (int k0 = 0; k0 < KP; k0 += 32) {
        // stage 64 rows x 32 k of x as bf16 (coalesced: 8 threads per row, 16B each)
        for (int i = tid; i < 512; i += 256) {
            int rl = i >> 3, seg = i & 7;
            int gr = row0 + rl, gk = k0 + seg * 4;
            uint2 pk = make_uint2(0u, 0u);
            if (gr < N && gk < K) {               // K%4==0: gk<K => gk+4<=K
                float4 v = *(const float4*)(x + (size_t)gr * K + gk);
                pk.x = f2bf_pair(v.x, v.y);
                pk.y = f2bf_pair(v.z, v.w);
            }
            *(uint2*)&xls[rl][seg * 4] = pk;
        }
        __syncthreads();
        ABfrag a;
        a.s = *(const short8v*)&xls[lrow][kgrp];
        int koff = k0 + kgrp;
        ABfrag b0, b1, b2, b3;
        b0.s = *(const short8v*)&w1t[(0 * 16 + (lane & 15)) * 168 + koff];
        b1.s = *(const short8v*)&w1t[(1 * 16 + (lane & 15)) * 168 + koff];
        b2.s = *(const short8v*)&w1t[(2 * 16 + (lane & 15)) * 168 + koff];
        b3.s = *(const short8v*)&w1t[(3 * 16 + (lane & 15)) * 168 + koff];
        acc0 = __builtin_amdgcn_mfma_f32_16x16x32_bf16(a.s, b0.s, acc0, 0, 0, 0);
        acc1 = __builtin_amdgcn_mfma_f32_16x16x32_bf16(a.s, b1.s, acc1, 0, 0, 0);
        acc2 = __builtin_amdgcn_mfma_f32_16x16x32_bf16(a.s, b2.s, acc2, 0, 0, 0);
        acc3 = __builtin_amdgcn_mfma_f32_16x16x32_bf16(a.s, b3.s, acc3, 0, 0, 0);
        __syncthreads();
    }
    // epilogue: C layout col = lane&15, row = (lane>>4)*4 + reg (overlay onto smem)
    int r4 = (lane >> 4) * 4;
#pragma unroll
    for (int r = 0; r < 4; r++) {
        ls[w][r4 + r][0 * 16 + (lane & 15)] = acc0[r];
        ls[w][r4 + r][1 * 16 + (lane & 15)] = acc1[r];
        ls[w][r4 + r][2 * 16 + (lane & 15)] = acc2[r];
        ls[w][r4 + r][3 * 16 + (lane & 15)] = acc3[r];
    }
    __syncthreads();
    int prow = lane >> 2, cg = lane & 3;
    int row = row0 + w * 16 + prow;
    if (row < N) {
        float dv = dinv[row];
        const float* lr = &ls[w][prow][cg * 16];
        uint4 o;
        o.x = pack4_fp8(lr[0] * dv, lr[1] * dv, lr[2] * dv, lr[3] * dv);
        o.y = pack4_fp8(lr[4] * dv, lr[5] * dv, lr[6] * dv, lr[7] * dv);
        o.z = pack4_fp8(lr[8] * dv, lr[9] * dv, lr[10] * dv, lr[11] * dv);
        o.w = pack4_fp8(lr[12] * dv, lr[13] * dv, lr[14] * dv, lr[15] * dv);
        if (cg < 2) ((uint4*)(hsA + (size_t)row * 8))[cg] = o;
        else        ((uint4*)(hsB + (size_t)row * 8))[cg - 2] = o;
    }
}

// ---------------- MFMA GEMM layer 2: buf bf16 [N][64] @ W2 -> fp8 half rows ----------------
__global__ void gemm2_mfma(const unsigned int* __restrict__ in, int K, int H,
                           const unsigned short* __restrict__ w2t,
                           const float* __restrict__ dinv,
                           unsigned int* __restrict__ hsA,
                           unsigned int* __restrict__ hsB, int N) {
    const int KP = 64;
    __shared__ float ls[4][16][64];   // 16384 B
    int tid = threadIdx.x;
    int w = tid >> 6, lane = tid & 63;
    int row0 = blockIdx.x * 64 + w * 16;

    int arow = row0 + (lane & 15);
    int kgrp = (lane >> 4) * 8;
    f32x4 acc0 = 0.0f, acc1 = 0.0f, acc2 = 0.0f, acc3 = 0.0f;
#pragma unroll
    for (int k0 = 0; k0 < KP; k0 += 32) {
        int koff = k0 + kgrp;
        ABfrag a; a.u[0] = 0; a.u[1] = 0; a.u[2] = 0; a.u[3] = 0;
        if (arow < N) {
            uint4 v = *(const uint4*)(in + (size_t)arow * 32 + (koff >> 1));  // 8 bf16
            a.u[0] = v.x; a.u[1] = v.y; a.u[2] = v.z; a.u[3] = v.w;
        }
        ABfrag b0, b1, b2, b3;
        b0.s = *(const short8v*)&w2t[(0 * 16 + (lane & 15)) * 72 + koff];
        b1.s = *(const short8v*)&w2t[(1 * 16 + (lane & 15)) * 72 + koff];
        b2.s = *(const short8v*)&w2t[(2 * 16 + (lane & 15)) * 72 + koff];
        b3.s = *(const short8v*)&w2t[(3 * 16 + (lane & 15)) * 72 + koff];
        acc0 = __builtin_amdgcn_mfma_f32_16x16x32_bf16(a.s, b0.s, acc0, 0, 0, 0);
        acc1 = __builtin_amdgcn_mfma_f32_16x16x32_bf16(a.s, b1.s, acc1, 0, 0, 0);
        acc2 = __builtin_amdgcn_mfma_f32_16x16x32_bf16(a.s, b2.s, acc2, 0, 0, 0);
        acc3 = __builtin_amdgcn_mfma_f32_16x16x32_bf16(a.s, b3.s, acc3, 0, 0, 0);
    }
    int r4 = (lane >> 4) * 4;
#pragma unroll
    for (int r = 0; r < 4; r++) {
        ls[w][r4 + r][0 * 16 + (lane & 15)] = acc0[r];
        ls[w][r4 + r][1 * 16 + (lane & 15)] = acc1[r];
        ls[w][r4 + r][2 * 16 + (lane & 15)] = acc2[r];
        ls[w][r4 + r][3 * 16 + (lane & 15)] = acc3[r];
    }
    __syncthreads();
    int prow = lane >> 2, cg = lane & 3;
    int row = row0 + prow;
    if (row < N) {
        float dv = dinv[row];
        const float* lr = &ls[w][prow][cg * 16];
        uint4 o;
        o.x = pack4_fp8(lr[0] * dv, lr[1] * dv, lr[2] * dv, lr[3] * dv);
        o.y = pack4_fp8(lr[4] * dv, lr[5] * dv, lr[6] * dv, lr[7] * dv);
        o.z = pack4_fp8(lr[8] * dv, lr[9] * dv, lr[10] * dv, lr[11] * dv);
        o.w = pack4_fp8(lr[12] * dv, lr[13] * dv, lr[14] * dv, lr[15] * dv);
        if (cg < 2) ((uint4*)(hsA + (size_t)row * 8))[cg] = o;
        else        ((uint4*)(hsB + (size_t)row * 8))[cg - 2] = o;
    }
}

// ---------------- aggregation over one fp8 half (32B rows, L2-resident) ----------------
__global__ void agg_half_kernel(const unsigned int* __restrict__ hsh,
                                const int* __restrict__ rowptr, const int* __restrict__ colidx,
                                const float* __restrict__ dinv, const float* __restrict__ bias,
                                int cbase, unsigned int* __restrict__ outbuf, int N) {
    int t = blockIdx.x * blockDim.x + threadIdx.x;
    int node = t >> 3;
    int q = t & 7;
    if (node >= N) return;
    const unsigned int* basq = hsh + q;
    unsigned int sv = basq[(size_t)node * 8];   // self loop term
    floatx2 plo = __builtin_amdgcn_cvt_pk_f32_fp8((int)sv, false);
    floatx2 phi = __builtin_amdgcn_cvt_pk_f32_fp8((int)sv, true);
    float a0 = plo[0], a1 = plo[1], a2 = phi[0], a3 = phi[1];
    int beg = rowptr[node], end = rowptr[node + 1];
    int e = beg;
    for (; e + 4 <= end; e += 4) {
        int s0 = colidx[e], s1 = colidx[e + 1], s2 = colidx[e + 2], s3 = colidx[e + 3];
        unsigned int v0 = basq[(size_t)s0 * 8];
        unsigned int v1 = basq[(size_t)s1 * 8];
        unsigned int v2 = basq[(size_t)s2 * 8];
        unsigned int v3 = basq[(size_t)s3 * 8];
        floatx2 l0 = __builtin_amdgcn_cvt_pk_f32_fp8((int)v0, false);
        floatx2 h0 = __builtin_amdgcn_cvt_pk_f32_fp8((int)v0, true);
        floatx2 l1 = __builtin_amdgcn_cvt_pk_f32_fp8((int)v1, false);
        floatx2 h1 = __builtin_amdgcn_cvt_pk_f32_fp8((int)v1, true);
        floatx2 l2 = __builtin_amdgcn_cvt_pk_f32_fp8((int)v2, false);
        floatx2 h2 = __builtin_amdgcn_cvt_pk_f32_fp8((int)v2, true);
        floatx2 l3 = __builtin_amdgcn_cvt_pk_f32_fp8((int)v3, false);
        floatx2 h3 = __builtin_amdgcn_cvt_pk_f32_fp8((int)v3, true);
        a0 += (l0[0] + l1[0]) + (l2[0] + l3[0]);
        a1 += (l0[1] + l1[1]) + (l2[1] + l3[1]);
        a2 += (h0[0] + h1[0]) + (h2[0] + h3[0]);
        a3 += (h0[1] + h1[1]) + (h2[1] + h3[1]);
    }
    for (; e < end; e++) {
        int s0 = colidx[e];
        unsigned int v0 = basq[(size_t)s0 * 8];
        floatx2 l0 = __builtin_amdgcn_cvt_pk_f32_fp8((int)v0, false);
        floatx2 h0 = __builtin_amdgcn_cvt_pk_f32_fp8((int)v0, true);
        a0 += l0[0]; a1 += l0[1]; a2 += h0[0]; a3 += h0[1];
    }
    float dv = dinv[node];
    int c0 = cbase + q * 4;
    float b0 = (c0 + 0 < HH) ? bias[c0 + 0] : 0.0f;
    float b1 = (c0 + 1 < HH) ? bias[c0 + 1] : 0.0f;
    float b2 = (c0 + 2 < HH) ? bias[c0 + 2] : 0.0f;
    float b3 = (c0 + 3 < HH) ? bias[c0 + 3] : 0.0f;
    float r0 = fmaxf(a0 * dv + b0, 0.0f);
    float r1 = fmaxf(a1 * dv + b1, 0.0f);
    float r2 = fmaxf(a2 * dv + b2, 0.0f);
    float r3 = fmaxf(a3 * dv + b3, 0.0f);
    uint2 w;
    if (c0 >= HH) { w.x = 0u; w.y = 0u; }
    else { w.x = f2bf_pair(r0, r1); w.y = f2bf_pair(r2, r3); }
    ((uint2*)outbuf)[(size_t)node * 16 + (cbase >> 2) + q] = w;
}

// ---------------- pooling + head over bf16 rows (bounds searched inline) ----------------
__global__ void pool_head_kernel(const unsigned int* __restrict__ h,
                                 const int* __restrict__ batch, int N,
                                 const float* __restrict__ Wl, const float* __restrict__ bl,
                                 float* __restrict__ out, int G) {
    __shared__ float4 red[16][16];    // [sub][q]
    int b = blockIdx.x;
    int t = threadIdx.x;
    int sub = t >> 4, q = t & 15;
    int beg, end;
    {
        int lo = 0, hi = N;
        while (lo < hi) { int mid = (lo + hi) >> 1; if (batch[mid] < b) lo = mid + 1; else hi = mid; }
        beg = lo;
        lo = 0; hi = N;
        while (lo < hi) { int mid = (lo + hi) >> 1; if (batch[mid] < b + 1) lo = mid + 1; else hi = mid; }
        end = lo;
    }
    const uint2* base = (const uint2*)h;
    float4 acc = make_float4(0.f, 0.f, 0.f, 0.f);
    for (int node = beg + sub; node < end; node += 16) {
        uint2 v = base[(size_t)node * 16 + q];
        acc.x += bf_lo(v.x); acc.y += bf_hi(v.x); acc.z += bf_lo(v.y); acc.w += bf_hi(v.y);
    }
    red[sub][q] = acc;
    __syncthreads();
#pragma unroll
    for (int off = 8; off >= 1; off >>= 1) {
        if (sub < off) {
            float4 a = red[sub][q], c = red[sub + off][q];
            a.x += c.x; a.y += c.y; a.z += c.z; a.w += c.w;
            red[sub][q] = a;
        }
        __syncthreads();
    }
    if (t == 0) {
        const float* g = (const float*)&red[0][0];
        float dot = 0.0f;
        for (int c = 0; c < HH; c++) dot += g[c] * Wl[c];
        float cnt = (float)(end - beg);
        float x = dot / fmaxf(cnt, 1.0f) + bl[0];
        out[b] = 1.0f / (1.0f + expf(-x));
    }
}

extern "C" void kernel_launch(void* const* d_in, const int* in_sizes, int n_in,
                              void* d_out, int out_size, void* d_ws, size_t ws_size,
                              hipStream_t stream) {
    const float* x     = (const float*)d_in[0];
    const int*   ei    = (const int*)d_in[1];
    const int*   batch = (const int*)d_in[2];
    const float* W1    = (const float*)d_in[3];
    const float* b1    = (const float*)d_in[4];
    const float* W2    = (const float*)d_in[5];
    const float* b2    = (const float*)d_in[6];
    const float* Wl    = (const float*)d_in[7];
    const float* bl    = (const float*)d_in[8];
    float* out = (float*)d_out;

    int N = in_sizes[2];
    int E = in_sizes[1] / 2;
    int F = in_sizes[0] / N;       // 136
    int G = out_size;              // 256 graphs

    int NB = (N + BSZ - 1) >> BSH;    // ~391 buckets
    int NC = (E + CH - 1) / CH;       // ~391 chunks
    int M  = NB * NC;
    int NS = (M + SCH - 1) / SCH;     // <=64 for this size

    char* ws = (char*)d_ws;
    size_t off = 0;
    auto alloc = [&](size_t bytes) -> void* {
        void* p = ws + off;
        off += (bytes + 255) & ~(size_t)255;
        return p;
    };
    size_t halfBytes = (size_t)N * 32;       // fp8 half rows (32B)
    size_t bufBytes  = (size_t)N * 128;      // bf16 rows (128B)
    size_t ebufBytes = (size_t)E * 4;
    float*          dinv      = (float*)alloc((size_t)N * 4);
    int*            rowptr    = (int*)alloc((size_t)(N + 1) * 4);
    int*            colidx    = (int*)alloc(ebufBytes);
    unsigned int*   hsA       = (unsigned int*)alloc(halfBytes);
    unsigned int*   hsB       = (unsigned int*)alloc(halfBytes);
    unsigned int*   buf       = (unsigned int*)alloc(bufBytes > ebufBytes ? bufBytes : ebufBytes);
    int*            blockHist = (int*)alloc((size_t)M * 4);
    int*            scanned   = (int*)alloc((size_t)M * 4);
    int*            csum      = (int*)alloc((size_t)NS * 4 + 256);
    unsigned short* w1t       = (unsigned short*)alloc(64 * 168 * 2);
    unsigned short* w2t       = (unsigned short*)alloc(64 * 72 * 2);
    int*            ebuf      = (int*)buf;    // alias: dead before first agg writes buf

    // CSR build (by dst), no global atomics
    histA_kernel<<<NC, 256, 0, stream>>>(ei, E, NB, NC, blockHist);
    scan1_kernel<<<NS, 256, 0, stream>>>(blockHist, M, csum);
    scan2_kernel<<<1, 64, 0, stream>>>(csum, NS, rowptr, N, E);
    scan3_kernel<<<NS, 256, 0, stream>>>(blockHist, M, csum, scanned);
    scatterB_kernel<<<NC, 512, 0, stream>>>(ei, E, NB, NC, blockHist, scanned, ebuf);
    buildC_kernel<<<NB, 512, 0, stream>>>(ebuf, scanned, NB, NC, N, E, rowptr, dinv, colidx);
    prepW_kernel<<<42, 256, 0, stream>>>(W1, F, HH, W2, HH, w1t, w2t);

    int aggBlocks = ((N * 8) + 255) / 256;
    int mfmaBlocks = (N + 63) / 64;

    // layer 1
    gemm1_mfma<<<mfmaBlocks, 256, 0, stream>>>(x, F, HH, w1t, dinv, hsA, hsB, N);
    agg_half_kernel<<<aggBlocks, 256, 0, stream>>>(hsA, rowptr, colidx, dinv, b1, 0,  buf, N);
    agg_half_kernel<<<aggBlocks, 256, 0, stream>>>(hsB, rowptr, colidx, dinv, b1, 32, buf, N);

    // layer 2
    gemm2_mfma<<<mfmaBlocks, 256, 0, stream>>>(buf, HH, HH, w2t, dinv, hsA, hsB, N);
    agg_half_kernel<<<aggBlocks, 256, 0, stream>>>(hsA, rowptr, colidx, dinv, b2, 0,  buf, N);
    agg_half_kernel<<<aggBlocks, 256, 0, stream>>>(hsB, rowptr, colidx, dinv, b2, 32, buf, N);

    // pooling + fused head
    pool_head_kernel<<<G, 256, 0, stream>>>(buf, batch, N, Wl, bl, out, G);
}

// Round 19
// 220.430 us; speedup vs baseline: 1.1390x; 1.0488x over previous
//
#include <hip/hip_runtime.h>
#include <math.h>

#define HH 50     // hidden features
#define BSH 8     // bucket shift: 256 nodes per bucket
#define BSZ 256
#define CH 8192   // edges per chunk in bucketed CSR build (LDS epack = 32KB)
#define SCH 4096  // entries per block in device-wide scan (256 thr x 16)

typedef float floatx2 __attribute__((ext_vector_type(2)));
typedef float f32x4 __attribute__((ext_vector_type(4)));
typedef short short8v __attribute__((ext_vector_type(8)));

union ABfrag { short8v s; unsigned int u[4]; };

__device__ __forceinline__ unsigned int f2bf_pair(float f0, float f1) {
    unsigned int u0 = __float_as_uint(f0);
    unsigned int u1 = __float_as_uint(f1);
    u0 = (u0 + 0x7FFFu + ((u0 >> 16) & 1u)) >> 16;   // RNE
    u1 = (u1 + 0x7FFFu + ((u1 >> 16) & 1u)) >> 16;
    return u0 | (u1 << 16);
}
__device__ __forceinline__ float bf_lo(unsigned int p) { return __uint_as_float(p << 16); }
__device__ __forceinline__ float bf_hi(unsigned int p) { return __uint_as_float(p & 0xFFFF0000u); }

__device__ __forceinline__ unsigned int pack4_fp8(float f0, float f1, float f2, float f3) {
    int r = 0;
    r = __builtin_amdgcn_cvt_pk_fp8_f32(f0, f1, r, false);
    r = __builtin_amdgcn_cvt_pk_fp8_f32(f2, f3, r, true);
    return (unsigned int)r;
}

// ---------------- bucketed CSR build (no global atomics) ----------------
__global__ void histA_kernel(const int* __restrict__ ei, int E, int NB, int NC,
                             int* __restrict__ blockHist) {
    __shared__ int hist[512];
    int c = blockIdx.x;
    int tid = threadIdx.x;
    for (int i = tid; i < 512; i += 256) hist[i] = 0;
    __syncthreads();
    int beg = c * CH, end = min(E, beg + CH);
    for (int i = beg + tid; i < end; i += 256) {
        int d = ei[(size_t)E + i];
        atomicAdd(&hist[d >> BSH], 1);
    }
    __syncthreads();
    for (int i = tid; i < NB; i += 256) blockHist[i * NC + c] = hist[i];   // bucket-major
}

// ---- device-wide exclusive scan of blockHist ----
__global__ void scan1_kernel(const int* __restrict__ bh, int M, int* __restrict__ csum) {
    __shared__ int red[4];
    int tid = threadIdx.x;
    int lane = tid & 63, wv = tid >> 6;
    int base = blockIdx.x * SCH + tid * 16;
    int s = 0;
    if (base + 16 <= M) {
#pragma unroll
        for (int j = 0; j < 4; j++) {
            int4 v = *(const int4*)(bh + base + 4 * j);
            s += v.x + v.y + v.z + v.w;
        }
    } else {
        for (int j = 0; j < 16 && base + j < M; j++) s += bh[base + j];
    }
    for (int off = 1; off < 64; off <<= 1) s += __shfl_xor(s, off);
    if (lane == 0) red[wv] = s;
    __syncthreads();
    if (tid == 0) csum[blockIdx.x] = red[0] + red[1] + red[2] + red[3];
}

// block 0 (lanes < 64): exclusive scan of chunk sums; blocks >= 1: W transpose to bf16.
__global__ void scan2_prepW_kernel(int* __restrict__ csum, int nb,
                                   int* __restrict__ rowptr, int N, int E,
                                   const float* __restrict__ W1, int K1, int H,
                                   const float* __restrict__ W2, int K2,
                                   unsigned short* __restrict__ w1t,
                                   unsigned short* __restrict__ w2t) {
    if (blockIdx.x == 0) {
        int lane = threadIdx.x;
        if (lane < 64) {
            int v = (lane < nb) ? csum[lane] : 0;
            int orig = v;
            for (int off = 1; off < 64; off <<= 1) {
                int u = __shfl_up(v, off);
                if (lane >= off) v += u;
            }
            if (lane < nb) csum[lane] = v - orig;
            if (lane == 0) rowptr[N] = E;
        }
        return;
    }
    int i = (blockIdx.x - 1) * 256 + threadIdx.x;
    if (i < 64 * 168) {
        int col = i / 168, k = i % 168;
        float v = (k < K1 && col < H) ? W1[k * H + col] : 0.0f;
        w1t[col * 168 + k] = (unsigned short)(f2bf_pair(v, 0.0f) & 0xFFFFu);
    }
    if (i < 64 * 72) {
        int col = i / 72, k = i % 72;
        float v = (k < K2 && col < H) ? W2[k * H + col] : 0.0f;
        w2t[col * 72 + k] = (unsigned short)(f2bf_pair(v, 0.0f) & 0xFFFFu);
    }
}

__global__ void scan3_kernel(const int* __restrict__ bh, int M, const int* __restrict__ csum,
                             int* __restrict__ scanned) {
    __shared__ int wsum[4];
    int tid = threadIdx.x;
    int lane = tid & 63, wv = tid >> 6;
    int base = blockIdx.x * SCH + tid * 16;
    int a[16];
#pragma unroll
    for (int j = 0; j < 16; j++) a[j] = 0;
    if (base + 16 <= M) {
#pragma unroll
        for (int j = 0; j < 4; j++) {
            int4 v = *(const int4*)(bh + base + 4 * j);
            a[4 * j] = v.x; a[4 * j + 1] = v.y; a[4 * j + 2] = v.z; a[4 * j + 3] = v.w;
        }
    } else {
        for (int j = 0; j < 16 && base + j < M; j++) a[j] = bh[base + j];
    }
    int t = 0;
#pragma unroll
    for (int j = 0; j < 16; j++) t += a[j];
    int inc = t;
    for (int off = 1; off < 64; off <<= 1) {
        int u = __shfl_up(inc, off);
        if (lane >= off) inc += u;
    }
    if (lane == 63) wsum[wv] = inc;
    __syncthreads();
    int wb = 0;
    for (int w = 0; w < wv; w++) wb += wsum[w];
    int run = csum[blockIdx.x] + wb + (inc - t);
    if (base + 16 <= M) {
#pragma unroll
        for (int j = 0; j < 4; j++) {
            int4 o;
            o.x = run; run += a[4 * j];
            o.y = run; run += a[4 * j + 1];
            o.z = run; run += a[4 * j + 2];
            o.w = run; run += a[4 * j + 3];
            *(int4*)(scanned + base + 4 * j) = o;
        }
    } else {
        for (int j = 0; j < 16 && base + j < M; j++) { scanned[base + j] = run; run += a[j]; }
    }
}

// ---- scatter: LDS-sort chunk by bucket, then fully-coalesced ordered copy-out ----
__global__ void scatterB_kernel(const int* __restrict__ ei, int E, int NB, int NC,
                                const int* __restrict__ blockHist,
                                const int* __restrict__ scanned, int* __restrict__ ebuf) {
    __shared__ int part[512];
    __shared__ int lofs[512];
    __shared__ int gofs[512];
    __shared__ int cur[512];
    __shared__ int epack[CH];
    int c = blockIdx.x;
    int tid = threadIdx.x;        // 512 threads
    int v = (tid < NB) ? blockHist[tid * NC + c] : 0;
    part[tid] = v;
    __syncthreads();
    for (int off = 1; off < 512; off <<= 1) {
        int u = (tid >= off) ? part[tid - off] : 0;
        __syncthreads();
        part[tid] += u;
        __syncthreads();
    }
    int ex = (tid == 0) ? 0 : part[tid - 1];
    lofs[tid] = ex;
    cur[tid] = ex;
    if (tid < NB) gofs[tid] = scanned[tid * NC + c];
    __syncthreads();
    int beg = c * CH, end = min(E, beg + CH), len = end - beg;
    for (int i = beg + tid; i < end; i += 512) {
        int s = ei[i];
        int d = ei[(size_t)E + i];
        int b = d >> BSH;
        int pos = atomicAdd(&cur[b], 1);
        epack[pos] = ((d & (BSZ - 1)) << 17) | s;
    }
    __syncthreads();
    for (int j = tid; j < len; j += 512) {
        int lo = 0, hi = NB - 1;
        while (lo < hi) { int mid = (lo + hi + 1) >> 1; if (lofs[mid] <= j) lo = mid; else hi = mid - 1; }
        ebuf[gofs[lo] + (j - lofs[lo])] = epack[j];
    }
}

__global__ void buildC_kernel(const int* __restrict__ ebuf, const int* __restrict__ scanned,
                              int NB, int NC, int N, int E,
                              int* __restrict__ rowptr, float* __restrict__ dinv,
                              int* __restrict__ colidx) {
    __shared__ int cnt[BSZ], woff[BSZ], part[BSZ];
    int b = blockIdx.x;
    int tid = threadIdx.x;
    int ebeg = scanned[b * NC];
    int eend = (b == NB - 1) ? E : scanned[(b + 1) * NC];
    if (tid < BSZ) cnt[tid] = 0;
    __syncthreads();
    for (int i = ebeg + tid; i < eend; i += 512) {
        atomicAdd(&cnt[ebuf[i] >> 17], 1);
    }
    __syncthreads();
    if (tid < BSZ) part[tid] = cnt[tid];
    __syncthreads();
    for (int off = 1; off < BSZ; off <<= 1) {
        int v = 0;
        if (tid < BSZ && tid >= off) v = part[tid - off];
        __syncthreads();
        if (tid < BSZ) part[tid] += v;
        __syncthreads();
    }
    if (tid < BSZ) {
        int ex = (tid == 0) ? 0 : part[tid - 1];
        woff[tid] = ex;
        int node = (b << BSH) + tid;
        if (node < N) {
            rowptr[node] = ebeg + ex;
            dinv[node] = 1.0f / sqrtf((float)(cnt[tid] + 1));   // +1 self loop
        }
    }
    __syncthreads();
    for (int i = ebeg + tid; i < eend; i += 512) {
        int p = ebuf[i];
        int dl = p >> 17;
        int s = p & 0x1FFFF;
        int pos = atomicAdd(&woff[dl], 1);
        colidx[ebeg + pos] = s;
    }
}

// ---------------- MFMA GEMM layer 1: x fp32 [N][136] @ W1 -> fp8 half rows ----------------
__global__ void gemm1_mfma(const float* __restrict__ x, int K, int H,
                           const unsigned short* __restrict__ w1t,
                           const float* __restrict__ dinv,
                           unsigned int* __restrict__ hsA,
                           unsigned int* __restrict__ hsB, int N) {
    const int KP = 160, LSS = 68;
    __shared__ __align__(16) char smem[4 * 16 * LSS * 4];   // 17408 B
    unsigned short (*xls)[40] = (unsigned short (*)[40])smem;     // 5120 B overlay
    float (*ls)[16][LSS] = (float (*)[16][LSS])smem;              // epilogue overlay
    int tid = threadIdx.x;
    int w = tid >> 6, lane = tid & 63;
    int row0 = blockIdx.x * 64;

    int lrow = w * 16 + (lane & 15);
    int kgrp = (lane >> 4) * 8;
    f32x4 acc0 = 0.0f, acc1 = 0.0f, acc2 = 0.0f, acc3 = 0.0f;
#pragma unroll
    for (int k0 = 0; k0 < KP; k0 += 32) {
        for (int i = tid; i < 512; i += 256) {
            int rl = i >> 3, seg = i & 7;
            int gr = row0 + rl, gk = k0 + seg * 4;
            uint2 pk = make_uint2(0u, 0u);
            if (gr < N && gk < K) {
                float4 v = *(const float4*)(x + (size_t)gr * K + gk);
                pk.x = f2bf_pair(v.x, v.y);
                pk.y = f2bf_pair(v.z, v.w);
            }
            *(uint2*)&xls[rl][seg * 4] = pk;
        }
        __syncthreads();
        ABfrag a;
        a.s = *(const short8v*)&xls[lrow][kgrp];
        int koff = k0 + kgrp;
        ABfrag b0, b1, b2, b3;
        b0.s = *(const short8v*)&w1t[(0 * 16 + (lane & 15)) * 168 + koff];
        b1.s = *(const short8v*)&w1t[(1 * 16 + (lane & 15)) * 168 + koff];
        b2.s = *(const short8v*)&w1t[(2 * 16 + (lane & 15)) * 168 + koff];
        b3.s = *(const short8v*)&w1t[(3 * 16 + (lane & 15)) * 168 + koff];
        acc0 = __builtin_amdgcn_mfma_f32_16x16x32_bf16(a.s, b0.s, acc0, 0, 0, 0);
        acc1 = __builtin_amdgcn_mfma_f32_16x16x32_bf16(a.s, b1.s, acc1, 0, 0, 0);
        acc2 = __builtin_amdgcn_mfma_f32_16x16x32_bf16(a.s, b2.s, acc2, 0, 0, 0);
        acc3 = __builtin_amdgcn_mfma_f32_16x16x32_bf16(a.s, b3.s, acc3, 0, 0, 0);
        __syncthreads();
    }
    int r4 = (lane >> 4) * 4;
#pragma unroll
    for (int r = 0; r < 4; r++) {
        ls[w][r4 + r][0 * 16 + (lane & 15)] = acc0[r];
        ls[w][r4 + r][1 * 16 + (lane & 15)] = acc1[r];
        ls[w][r4 + r][2 * 16 + (lane & 15)] = acc2[r];
        ls[w][r4 + r][3 * 16 + (lane & 15)] = acc3[r];
    }
    __syncthreads();
    int prow = lane >> 2, cg = lane & 3;
    int row = row0 + w * 16 + prow;
    if (row < N) {
        float dv = dinv[row];
        const float* lr = &ls[w][prow][cg * 16];
        uint4 o;
        o.x = pack4_fp8(lr[0] * dv, lr[1] * dv, lr[2] * dv, lr[3] * dv);
        o.y = pack4_fp8(lr[4] * dv, lr[5] * dv, lr[6] * dv, lr[7] * dv);
        o.z = pack4_fp8(lr[8] * dv, lr[9] * dv, lr[10] * dv, lr[11] * dv);
        o.w = pack4_fp8(lr[12] * dv, lr[13] * dv, lr[14] * dv, lr[15] * dv);
        if (cg < 2) ((uint4*)(hsA + (size_t)row * 8))[cg] = o;
        else        ((uint4*)(hsB + (size_t)row * 8))[cg - 2] = o;
    }
}

// ---------------- MFMA GEMM layer 2: buf bf16 [N][64] @ W2 -> fp8 half rows ----------------
__global__ void gemm2_mfma(const unsigned int* __restrict__ in, int K, int H,
                           const unsigned short* __restrict__ w2t,
                           const float* __restrict__ dinv,
                           unsigned int* __restrict__ hsA,
                           unsigned int* __restrict__ hsB, int N) {
    const int KP = 64;
    __shared__ float ls[4][16][64];   // 16384 B
    int tid = threadIdx.x;
    int w = tid >> 6, lane = tid & 63;
    int row0 = blockIdx.x * 64 + w * 16;

    int arow = row0 + (lane & 15);
    int kgrp = (lane >> 4) * 8;
    f32x4 acc0 = 0.0f, acc1 = 0.0f, acc2 = 0.0f, acc3 = 0.0f;
#pragma unroll
    for (int k0 = 0; k0 < KP; k0 += 32) {
        int koff = k0 + kgrp;
        ABfrag a; a.u[0] = 0; a.u[1] = 0; a.u[2] = 0; a.u[3] = 0;
        if (arow < N) {
            uint4 v = *(const uint4*)(in + (size_t)arow * 32 + (koff >> 1));  // 8 bf16
            a.u[0] = v.x; a.u[1] = v.y; a.u[2] = v.z; a.u[3] = v.w;
        }
        ABfrag b0, b1, b2, b3;
        b0.s = *(const short8v*)&w2t[(0 * 16 + (lane & 15)) * 72 + koff];
        b1.s = *(const short8v*)&w2t[(1 * 16 + (lane & 15)) * 72 + koff];
        b2.s = *(const short8v*)&w2t[(2 * 16 + (lane & 15)) * 72 + koff];
        b3.s = *(const short8v*)&w2t[(3 * 16 + (lane & 15)) * 72 + koff];
        acc0 = __builtin_amdgcn_mfma_f32_16x16x32_bf16(a.s, b0.s, acc0, 0, 0, 0);
        acc1 = __builtin_amdgcn_mfma_f32_16x16x32_bf16(a.s, b1.s, acc1, 0, 0, 0);
        acc2 = __builtin_amdgcn_mfma_f32_16x16x32_bf16(a.s, b2.s, acc2, 0, 0, 0);
        acc3 = __builtin_amdgcn_mfma_f32_16x16x32_bf16(a.s, b3.s, acc3, 0, 0, 0);
    }
    int r4 = (lane >> 4) * 4;
#pragma unroll
    for (int r = 0; r < 4; r++) {
        ls[w][r4 + r][0 * 16 + (lane & 15)] = acc0[r];
        ls[w][r4 + r][1 * 16 + (lane & 15)] = acc1[r];
        ls[w][r4 + r][2 * 16 + (lane & 15)] = acc2[r];
        ls[w][r4 + r][3 * 16 + (lane & 15)] = acc3[r];
    }
    __syncthreads();
    int prow = lane >> 2, cg = lane & 3;
    int row = row0 + prow;
    if (row < N) {
        float dv = dinv[row];
        const float* lr = &ls[w][prow][cg * 16];
        uint4 o;
        o.x = pack4_fp8(lr[0] * dv, lr[1] * dv, lr[2] * dv, lr[3] * dv);
        o.y = pack4_fp8(lr[4] * dv, lr[5] * dv, lr[6] * dv, lr[7] * dv);
        o.z = pack4_fp8(lr[8] * dv, lr[9] * dv, lr[10] * dv, lr[11] * dv);
        o.w = pack4_fp8(lr[12] * dv, lr[13] * dv, lr[14] * dv, lr[15] * dv);
        if (cg < 2) ((uint4*)(hsA + (size_t)row * 8))[cg] = o;
        else        ((uint4*)(hsB + (size_t)row * 8))[cg - 2] = o;
    }
}

// ---------------- aggregation over one fp8 half (32B rows, L2-resident) ----------------
// int4-vectorized colidx + 8-deep gather unroll.
__global__ void agg_half_kernel(const unsigned int* __restrict__ hsh,
                                const int* __restrict__ rowptr, const int* __restrict__ colidx,
                                const float* __restrict__ dinv, const float* __restrict__ bias,
                                int cbase, unsigned int* __restrict__ outbuf, int N) {
    int t = blockIdx.x * blockDim.x + threadIdx.x;
    int node = t >> 3;
    int q = t & 7;
    if (node >= N) return;
    const unsigned int* basq = hsh + q;
    unsigned int sv = basq[(size_t)node * 8];   // self loop term
    floatx2 plo = __builtin_amdgcn_cvt_pk_f32_fp8((int)sv, false);
    floatx2 phi = __builtin_amdgcn_cvt_pk_f32_fp8((int)sv, true);
    float a0 = plo[0], a1 = plo[1], a2 = phi[0], a3 = phi[1];
    int beg = rowptr[node], end = rowptr[node + 1];
    int e = beg;
    // align e to 4 for int4 colidx loads
    for (; e < end && (e & 3); e++) {
        unsigned int v0 = basq[(size_t)colidx[e] * 8];
        floatx2 l0 = __builtin_amdgcn_cvt_pk_f32_fp8((int)v0, false);
        floatx2 h0 = __builtin_amdgcn_cvt_pk_f32_fp8((int)v0, true);
        a0 += l0[0]; a1 += l0[1]; a2 += h0[0]; a3 += h0[1];
    }
    for (; e + 8 <= end; e += 8) {
        int4 c0 = *(const int4*)(colidx + e);
        int4 c1 = *(const int4*)(colidx + e + 4);
        unsigned int v0 = basq[(size_t)c0.x * 8];
        unsigned int v1 = basq[(size_t)c0.y * 8];
        unsigned int v2 = basq[(size_t)c0.z * 8];
        unsigned int v3 = basq[(size_t)c0.w * 8];
        unsigned int v4 = basq[(size_t)c1.x * 8];
        unsigned int v5 = basq[(size_t)c1.y * 8];
        unsigned int v6 = basq[(size_t)c1.z * 8];
        unsigned int v7 = basq[(size_t)c1.w * 8];
        floatx2 l0 = __builtin_amdgcn_cvt_pk_f32_fp8((int)v0, false);
        floatx2 h0 = __builtin_amdgcn_cvt_pk_f32_fp8((int)v0, true);
        floatx2 l1 = __builtin_amdgcn_cvt_pk_f32_fp8((int)v1, false);
        floatx2 h1 = __builtin_amdgcn_cvt_pk_f32_fp8((int)v1, true);
        floatx2 l2 = __builtin_amdgcn_cvt_pk_f32_fp8((int)v2, false);
        floatx2 h2 = __builtin_amdgcn_cvt_pk_f32_fp8((int)v2, true);
        floatx2 l3 = __builtin_amdgcn_cvt_pk_f32_fp8((int)v3, false);
        floatx2 h3 = __builtin_amdgcn_cvt_pk_f32_fp8((int)v3, true);
        floatx2 l4 = __builtin_amdgcn_cvt_pk_f32_fp8((int)v4, false);
        floatx2 h4 = __builtin_amdgcn_cvt_pk_f32_fp8((int)v4, true);
        floatx2 l5 = __builtin_amdgcn_cvt_pk_f32_fp8((int)v5, false);
        floatx2 h5 = __builtin_amdgcn_cvt_pk_f32_fp8((int)v5, true);
        floatx2 l6 = __builtin_amdgcn_cvt_pk_f32_fp8((int)v6, false);
        floatx2 h6 = __builtin_amdgcn_cvt_pk_f32_fp8((int)v6, true);
        floatx2 l7 = __builtin_amdgcn_cvt_pk_f32_fp8((int)v7, false);
        floatx2 h7 = __builtin_amdgcn_cvt_pk_f32_fp8((int)v7, true);
        a0 += ((l0[0] + l1[0]) + (l2[0] + l3[0])) + ((l4[0] + l5[0]) + (l6[0] + l7[0]));
        a1 += ((l0[1] + l1[1]) + (l2[1] + l3[1])) + ((l4[1] + l5[1]) + (l6[1] + l7[1]));
        a2 += ((h0[0] + h1[0]) + (h2[0] + h3[0])) + ((h4[0] + h5[0]) + (h6[0] + h7[0]));
        a3 += ((h0[1] + h1[1]) + (h2[1] + h3[1])) + ((h4[1] + h5[1]) + (h6[1] + h7[1]));
    }
    if (e + 4 <= end) {
        int4 c0 = *(const int4*)(colidx + e);
        unsigned int v0 = basq[(size_t)c0.x * 8];
        unsigned int v1 = basq[(size_t)c0.y * 8];
        unsigned int v2 = basq[(size_t)c0.z * 8];
        unsigned int v3 = basq[(size_t)c0.w * 8];
        floatx2 l0 = __builtin_amdgcn_cvt_pk_f32_fp8((int)v0, false);
        floatx2 h0 = __builtin_amdgcn_cvt_pk_f32_fp8((int)v0, true);
        floatx2 l1 = __builtin_amdgcn_cvt_pk_f32_fp8((int)v1, false);
        floatx2 h1 = __builtin_amdgcn_cvt_pk_f32_fp8((int)v1, true);
        floatx2 l2 = __builtin_amdgcn_cvt_pk_f32_fp8((int)v2, false);
        floatx2 h2 = __builtin_amdgcn_cvt_pk_f32_fp8((int)v2, true);
        floatx2 l3 = __builtin_amdgcn_cvt_pk_f32_fp8((int)v3, false);
        floatx2 h3 = __builtin_amdgcn_cvt_pk_f32_fp8((int)v3, true);
        a0 += (l0[0] + l1[0]) + (l2[0] + l3[0]);
        a1 += (l0[1] + l1[1]) + (l2[1] + l3[1]);
        a2 += (h0[0] + h1[0]) + (h2[0] + h3[0]);
        a3 += (h0[1] + h1[1]) + (h2[1] + h3[1]);
        e += 4;
    }
    for (; e < end; e++) {
        unsigned int v0 = basq[(size_t)colidx[e] * 8];
        floatx2 l0 = __builtin_amdgcn_cvt_pk_f32_fp8((int)v0, false);
        floatx2 h0 = __builtin_amdgcn_cvt_pk_f32_fp8((int)v0, true);
        a0 += l0[0]; a1 += l0[1]; a2 += h0[0]; a3 += h0[1];
    }
    float dv = dinv[node];
    int c0 = cbase + q * 4;
    float b0 = (c0 + 0 < HH) ? bias[c0 + 0] : 0.0f;
    float b1 = (c0 + 1 < HH) ? bias[c0 + 1] : 0.0f;
    float b2 = (c0 + 2 < HH) ? bias[c0 + 2] : 0.0f;
    float b3 = (c0 + 3 < HH) ? bias[c0 + 3] : 0.0f;
    float r0 = fmaxf(a0 * dv + b0, 0.0f);
    float r1 = fmaxf(a1 * dv + b1, 0.0f);
    float r2 = fmaxf(a2 * dv + b2, 0.0f);
    float r3 = fmaxf(a3 * dv + b3, 0.0f);
    uint2 w;
    if (c0 >= HH) { w.x = 0u; w.y = 0u; }
    else { w.x = f2bf_pair(r0, r1); w.y = f2bf_pair(r2, r3); }
    ((uint2*)outbuf)[(size_t)node * 16 + (cbase >> 2) + q] = w;
}

// ---------------- pooling + head over bf16 rows (bounds searched inline) ----------------
__global__ void pool_head_kernel(const unsigned int* __restrict__ h,
                                 const int* __restrict__ batch, int N,
                                 const float* __restrict__ Wl, const float* __restrict__ bl,
                                 float* __restrict__ out, int G) {
    __shared__ float4 red[16][16];    // [sub][q]
    int b = blockIdx.x;
    int t = threadIdx.x;
    int sub = t >> 4, q = t & 15;
    int beg, end;
    {
        int lo = 0, hi = N;
        while (lo < hi) { int mid = (lo + hi) >> 1; if (batch[mid] < b) lo = mid + 1; else hi = mid; }
        beg = lo;
        lo = 0; hi = N;
        while (lo < hi) { int mid = (lo + hi) >> 1; if (batch[mid] < b + 1) lo = mid + 1; else hi = mid; }
        end = lo;
    }
    const uint2* base = (const uint2*)h;
    float4 acc = make_float4(0.f, 0.f, 0.f, 0.f);
    for (int node = beg + sub; node < end; node += 16) {
        uint2 v = base[(size_t)node * 16 + q];
        acc.x += bf_lo(v.x); acc.y += bf_hi(v.x); acc.z += bf_lo(v.y); acc.w += bf_hi(v.y);
    }
    red[sub][q] = acc;
    __syncthreads();
#pragma unroll
    for (int off = 8; off >= 1; off >>= 1) {
        if (sub < off) {
            float4 a = red[sub][q], c = red[sub + off][q];
            a.x += c.x; a.y += c.y; a.z += c.z; a.w += c.w;
            red[sub][q] = a;
        }
        __syncthreads();
    }
    if (t == 0) {
        const float* g = (const float*)&red[0][0];
        float dot = 0.0f;
        for (int c = 0; c < HH; c++) dot += g[c] * Wl[c];
        float cnt = (float)(end - beg);
        float x = dot / fmaxf(cnt, 1.0f) + bl[0];
        out[b] = 1.0f / (1.0f + expf(-x));
    }
}

extern "C" void kernel_launch(void* const* d_in, const int* in_sizes, int n_in,
                              void* d_out, int out_size, void* d_ws, size_t ws_size,
                              hipStream_t stream) {
    const float* x     = (const float*)d_in[0];
    const int*   ei    = (const int*)d_in[1];
    const int*   batch = (const int*)d_in[2];
    const float* W1    = (const float*)d_in[3];
    const float* b1    = (const float*)d_in[4];
    const float* W2    = (const float*)d_in[5];
    const float* b2    = (const float*)d_in[6];
    const float* Wl    = (const float*)d_in[7];
    const float* bl    = (const float*)d_in[8];
    float* out = (float*)d_out;

    int N = in_sizes[2];
    int E = in_sizes[1] / 2;
    int F = in_sizes[0] / N;       // 136
    int G = out_size;              // 256 graphs

    int NB = (N + BSZ - 1) >> BSH;    // ~391 buckets
    int NC = (E + CH - 1) / CH;       // ~391 chunks
    int M  = NB * NC;
    int NS = (M + SCH - 1) / SCH;     // <=64 for this size

    char* ws = (char*)d_ws;
    size_t off = 0;
    auto alloc = [&](size_t bytes) -> void* {
        void* p = ws + off;
        off += (bytes + 255) & ~(size_t)255;
        return p;
    };
    size_t halfBytes = (size_t)N * 32;       // fp8 half rows (32B)
    size_t bufBytes  = (size_t)N * 128;      // bf16 rows (128B)
    size_t ebufBytes = (size_t)E * 4;
    float*          dinv      = (float*)alloc((size_t)N * 4);
    int*            rowptr    = (int*)alloc((size_t)(N + 1) * 4);
    int*            colidx    = (int*)alloc(ebufBytes);
    unsigned int*   hsA       = (unsigned int*)alloc(halfBytes);
    unsigned int*   hsB       = (unsigned int*)alloc(halfBytes);
    unsigned int*   buf       = (unsigned int*)alloc(bufBytes > ebufBytes ? bufBytes : ebufBytes);
    int*            blockHist = (int*)alloc((size_t)M * 4);
    int*            scanned   = (int*)alloc((size_t)M * 4);
    int*            csum      = (int*)alloc((size_t)NS * 4 + 256);
    unsigned short* w1t       = (unsigned short*)alloc(64 * 168 * 2);
    unsigned short* w2t       = (unsigned short*)alloc(64 * 72 * 2);
    int*            ebuf      = (int*)buf;    // alias: dead before first agg writes buf

    // CSR build (by dst), no global atomics; scan2 block 0 + prepW blocks 1..60
    histA_kernel<<<NC, 256, 0, stream>>>(ei, E, NB, NC, blockHist);
    scan1_kernel<<<NS, 256, 0, stream>>>(blockHist, M, csum);
    scan2_prepW_kernel<<<61, 256, 0, stream>>>(csum, NS, rowptr, N, E,
                                               W1, F, HH, W2, HH, w1t, w2t);
    scan3_kernel<<<NS, 256, 0, stream>>>(blockHist, M, csum, scanned);
    scatterB_kernel<<<NC, 512, 0, stream>>>(ei, E, NB, NC, blockHist, scanned, ebuf);
    buildC_kernel<<<NB, 512, 0, stream>>>(ebuf, scanned, NB, NC, N, E, rowptr, dinv, colidx);

    int aggBlocks = ((N * 8) + 255) / 256;
    int mfmaBlocks = (N + 63) / 64;

    // layer 1
    gemm1_mfma<<<mfmaBlocks, 256, 0, stream>>>(x, F, HH, w1t, dinv, hsA, hsB, N);
    agg_half_kernel<<<aggBlocks, 256, 0, stream>>>(hsA, rowptr, colidx, dinv, b1, 0,  buf, N);
    agg_half_kernel<<<aggBlocks, 256, 0, stream>>>(hsB, rowptr, colidx, dinv, b1, 32, buf, N);

    // layer 2
    gemm2_mfma<<<mfmaBlocks, 256, 0, stream>>>(buf, HH, HH, w2t, dinv, hsA, hsB, N);
    agg_half_kernel<<<aggBlocks, 256, 0, stream>>>(hsA, rowptr, colidx, dinv, b2, 0,  buf, N);
    agg_half_kernel<<<aggBlocks, 256, 0, stream>>>(hsB, rowptr, colidx, dinv, b2, 32, buf, N);

    // pooling + fused head
    pool_head_kernel<<<G, 256, 0, stream>>>(buf, batch, N, Wl, bl, out, G);
}

// Round 20
// 220.373 us; speedup vs baseline: 1.1393x; 1.0003x over previous
//
#include <hip/hip_runtime.h>
#include <math.h>

#define HH 50     // hidden features
#define BSH 8     // bucket shift: 256 nodes per bucket
#define BSZ 256
#define CH 8192   // edges per chunk in bucketed CSR build (LDS epack = 32KB)
#define SCH 4096  // entries per block in device-wide scan (256 thr x 16)

typedef float floatx2 __attribute__((ext_vector_type(2)));
typedef float f32x4 __attribute__((ext_vector_type(4)));
typedef short short8v __attribute__((ext_vector_type(8)));

union ABfrag { short8v s; unsigned int u[4]; };

__device__ __forceinline__ unsigned int f2bf_pair(float f0, float f1) {
    unsigned int u0 = __float_as_uint(f0);
    unsigned int u1 = __float_as_uint(f1);
    u0 = (u0 + 0x7FFFu + ((u0 >> 16) & 1u)) >> 16;   // RNE
    u1 = (u1 + 0x7FFFu + ((u1 >> 16) & 1u)) >> 16;
    return u0 | (u1 << 16);
}
__device__ __forceinline__ float bf_lo(unsigned int p) { return __uint_as_float(p << 16); }
__device__ __forceinline__ float bf_hi(unsigned int p) { return __uint_as_float(p & 0xFFFF0000u); }

__device__ __forceinline__ unsigned int pack4_fp8(float f0, float f1, float f2, float f3) {
    int r = 0;
    r = __builtin_amdgcn_cvt_pk_fp8_f32(f0, f1, r, false);
    r = __builtin_amdgcn_cvt_pk_fp8_f32(f2, f3, r, true);
    return (unsigned int)r;
}

// ---------------- bucketed CSR build (no global atomics) ----------------
__global__ void histA_kernel(const int* __restrict__ ei, int E, int NB, int NC,
                             int* __restrict__ blockHist) {
    __shared__ int hist[512];
    int c = blockIdx.x;
    int tid = threadIdx.x;
    for (int i = tid; i < 512; i += 256) hist[i] = 0;
    __syncthreads();
    int beg = c * CH, end = min(E, beg + CH);
    for (int i = beg + tid; i < end; i += 256) {
        int d = ei[(size_t)E + i];
        atomicAdd(&hist[d >> BSH], 1);
    }
    __syncthreads();
    for (int i = tid; i < NB; i += 256) blockHist[i * NC + c] = hist[i];   // bucket-major
}

// ---- device-wide exclusive scan of blockHist ----
__global__ void scan1_kernel(const int* __restrict__ bh, int M, int* __restrict__ csum) {
    __shared__ int red[4];
    int tid = threadIdx.x;
    int lane = tid & 63, wv = tid >> 6;
    int base = blockIdx.x * SCH + tid * 16;
    int s = 0;
    if (base + 16 <= M) {
#pragma unroll
        for (int j = 0; j < 4; j++) {
            int4 v = *(const int4*)(bh + base + 4 * j);
            s += v.x + v.y + v.z + v.w;
        }
    } else {
        for (int j = 0; j < 16 && base + j < M; j++) s += bh[base + j];
    }
    for (int off = 1; off < 64; off <<= 1) s += __shfl_xor(s, off);
    if (lane == 0) red[wv] = s;
    __syncthreads();
    if (tid == 0) csum[blockIdx.x] = red[0] + red[1] + red[2] + red[3];
}

// block 0 (lanes < 64): exclusive scan of chunk sums; blocks >= 1: W transpose to bf16.
__global__ void scan2_prepW_kernel(int* __restrict__ csum, int nb,
                                   int* __restrict__ rowptr, int N, int E,
                                   const float* __restrict__ W1, int K1, int H,
                                   const float* __restrict__ W2, int K2,
                                   unsigned short* __restrict__ w1t,
                                   unsigned short* __restrict__ w2t) {
    if (blockIdx.x == 0) {
        int lane = threadIdx.x;
        if (lane < 64) {
            int v = (lane < nb) ? csum[lane] : 0;
            int orig = v;
            for (int off = 1; off < 64; off <<= 1) {
                int u = __shfl_up(v, off);
                if (lane >= off) v += u;
            }
            if (lane < nb) csum[lane] = v - orig;
            if (lane == 0) rowptr[N] = E;
        }
        return;
    }
    int i = (blockIdx.x - 1) * 256 + threadIdx.x;
    if (i < 64 * 168) {
        int col = i / 168, k = i % 168;
        float v = (k < K1 && col < H) ? W1[k * H + col] : 0.0f;
        w1t[col * 168 + k] = (unsigned short)(f2bf_pair(v, 0.0f) & 0xFFFFu);
    }
    if (i < 64 * 72) {
        int col = i / 72, k = i % 72;
        float v = (k < K2 && col < H) ? W2[k * H + col] : 0.0f;
        w2t[col * 72 + k] = (unsigned short)(f2bf_pair(v, 0.0f) & 0xFFFFu);
    }
}

__global__ void scan3_kernel(const int* __restrict__ bh, int M, const int* __restrict__ csum,
                             int* __restrict__ scanned) {
    __shared__ int wsum[4];
    int tid = threadIdx.x;
    int lane = tid & 63, wv = tid >> 6;
    int base = blockIdx.x * SCH + tid * 16;
    int a[16];
#pragma unroll
    for (int j = 0; j < 16; j++) a[j] = 0;
    if (base + 16 <= M) {
#pragma unroll
        for (int j = 0; j < 4; j++) {
            int4 v = *(const int4*)(bh + base + 4 * j);
            a[4 * j] = v.x; a[4 * j + 1] = v.y; a[4 * j + 2] = v.z; a[4 * j + 3] = v.w;
        }
    } else {
        for (int j = 0; j < 16 && base + j < M; j++) a[j] = bh[base + j];
    }
    int t = 0;
#pragma unroll
    for (int j = 0; j < 16; j++) t += a[j];
    int inc = t;
    for (int off = 1; off < 64; off <<= 1) {
        int u = __shfl_up(inc, off);
        if (lane >= off) inc += u;
    }
    if (lane == 63) wsum[wv] = inc;
    __syncthreads();
    int wb = 0;
    for (int w = 0; w < wv; w++) wb += wsum[w];
    int run = csum[blockIdx.x] + wb + (inc - t);
    if (base + 16 <= M) {
#pragma unroll
        for (int j = 0; j < 4; j++) {
            int4 o;
            o.x = run; run += a[4 * j];
            o.y = run; run += a[4 * j + 1];
            o.z = run; run += a[4 * j + 2];
            o.w = run; run += a[4 * j + 3];
            *(int4*)(scanned + base + 4 * j) = o;
        }
    } else {
        for (int j = 0; j < 16 && base + j < M; j++) { scanned[base + j] = run; run += a[j]; }
    }
}

// ---- scatter: LDS-sort chunk by bucket, then fully-coalesced ordered copy-out ----
__global__ void scatterB_kernel(const int* __restrict__ ei, int E, int NB, int NC,
                                const int* __restrict__ blockHist,
                                const int* __restrict__ scanned, int* __restrict__ ebuf) {
    __shared__ int part[512];
    __shared__ int lofs[512];
    __shared__ int gofs[512];
    __shared__ int cur[512];
    __shared__ int epack[CH];
    int c = blockIdx.x;
    int tid = threadIdx.x;        // 512 threads
    int v = (tid < NB) ? blockHist[tid * NC + c] : 0;
    part[tid] = v;
    __syncthreads();
    for (int off = 1; off < 512; off <<= 1) {
        int u = (tid >= off) ? part[tid - off] : 0;
        __syncthreads();
        part[tid] += u;
        __syncthreads();
    }
    int ex = (tid == 0) ? 0 : part[tid - 1];
    lofs[tid] = ex;
    cur[tid] = ex;
    if (tid < NB) gofs[tid] = scanned[tid * NC + c];
    __syncthreads();
    int beg = c * CH, end = min(E, beg + CH), len = end - beg;
    for (int i = beg + tid; i < end; i += 512) {
        int s = ei[i];
        int d = ei[(size_t)E + i];
        int b = d >> BSH;
        int pos = atomicAdd(&cur[b], 1);
        epack[pos] = ((d & (BSZ - 1)) << 17) | s;
    }
    __syncthreads();
    for (int j = tid; j < len; j += 512) {
        int lo = 0, hi = NB - 1;
        while (lo < hi) { int mid = (lo + hi + 1) >> 1; if (lofs[mid] <= j) lo = mid; else hi = mid - 1; }
        ebuf[gofs[lo] + (j - lofs[lo])] = epack[j];
    }
}

__global__ void buildC_kernel(const int* __restrict__ ebuf, const int* __restrict__ scanned,
                              int NB, int NC, int N, int E,
                              int* __restrict__ rowptr, float* __restrict__ dinv,
                              int* __restrict__ colidx) {
    __shared__ int cnt[BSZ], woff[BSZ], part[BSZ];
    int b = blockIdx.x;
    int tid = threadIdx.x;
    int ebeg = scanned[b * NC];
    int eend = (b == NB - 1) ? E : scanned[(b + 1) * NC];
    if (tid < BSZ) cnt[tid] = 0;
    __syncthreads();
    for (int i = ebeg + tid; i < eend; i += 512) {
        atomicAdd(&cnt[ebuf[i] >> 17], 1);
    }
    __syncthreads();
    if (tid < BSZ) part[tid] = cnt[tid];
    __syncthreads();
    for (int off = 1; off < BSZ; off <<= 1) {
        int v = 0;
        if (tid < BSZ && tid >= off) v = part[tid - off];
        __syncthreads();
        if (tid < BSZ) part[tid] += v;
        __syncthreads();
    }
    if (tid < BSZ) {
        int ex = (tid == 0) ? 0 : part[tid - 1];
        woff[tid] = ex;
        int node = (b << BSH) + tid;
        if (node < N) {
            rowptr[node] = ebeg + ex;
            dinv[node] = 1.0f / sqrtf((float)(cnt[tid] + 1));   // +1 self loop
        }
    }
    __syncthreads();
    for (int i = ebeg + tid; i < eend; i += 512) {
        int p = ebuf[i];
        int dl = p >> 17;
        int s = p & 0x1FFFF;
        int pos = atomicAdd(&woff[dl], 1);
        colidx[ebeg + pos] = s;
    }
}

// ---------------- MFMA GEMM layer 1: x fp32 [N][136] @ W1 -> fp8 half rows ----------------
// Whole 64x136 x-panel staged once (bf16), ONE barrier, then barrier-free K-loop.
__global__ void gemm1_mfma(const float* __restrict__ x, int K, int H,
                           const unsigned short* __restrict__ w1t,
                           const float* __restrict__ dinv,
                           unsigned int* __restrict__ hsA,
                           unsigned int* __restrict__ hsB, int N) {
    const int KP = 160, XS = 168, LSS = 68;
    __shared__ __align__(16) char smem[64 * XS * 2];        // 21504 B
    unsigned short (*xls)[XS] = (unsigned short (*)[XS])smem;
    float (*ls)[16][LSS] = (float (*)[16][LSS])smem;        // epilogue overlay (17408 B)
    int tid = threadIdx.x;
    int w = tid >> 6, lane = tid & 63;
    int row0 = blockIdx.x * 64;

    // zero pad cols [136,168) (A must be 0-safe where w1t is 0-padded)
    for (int i = tid; i < 64 * 16; i += 256) {
        int row = i >> 4, c = i & 15;
        ((unsigned int*)&xls[row][136])[c] = 0u;
    }
    // stage full panel: 64 rows x 34 float4 (coalesced), cvt to bf16
    for (int i = tid; i < 64 * 34; i += 256) {
        int row = i / 34, kseg = i - row * 34;
        int gr = row0 + row;
        uint2 pk = make_uint2(0u, 0u);
        if (gr < N) {
            float4 v = *(const float4*)(x + (size_t)gr * K + kseg * 4);
            pk.x = f2bf_pair(v.x, v.y);
            pk.y = f2bf_pair(v.z, v.w);
        }
        *(uint2*)&xls[row][kseg * 4] = pk;
    }
    __syncthreads();

    int lrow = w * 16 + (lane & 15);
    int kgrp = (lane >> 4) * 8;
    f32x4 acc0 = 0.0f, acc1 = 0.0f, acc2 = 0.0f, acc3 = 0.0f;
#pragma unroll
    for (int k0 = 0; k0 < KP; k0 += 32) {
        int koff = k0 + kgrp;
        ABfrag a;
        a.s = *(const short8v*)&xls[lrow][koff];
        ABfrag b0, b1, b2, b3;
        b0.s = *(const short8v*)&w1t[(0 * 16 + (lane & 15)) * 168 + koff];
        b1.s = *(const short8v*)&w1t[(1 * 16 + (lane & 15)) * 168 + koff];
        b2.s = *(const short8v*)&w1t[(2 * 16 + (lane & 15)) * 168 + koff];
        b3.s = *(const short8v*)&w1t[(3 * 16 + (lane & 15)) * 168 + koff];
        acc0 = __builtin_amdgcn_mfma_f32_16x16x32_bf16(a.s, b0.s, acc0, 0, 0, 0);
        acc1 = __builtin_amdgcn_mfma_f32_16x16x32_bf16(a.s, b1.s, acc1, 0, 0, 0);
        acc2 = __builtin_amdgcn_mfma_f32_16x16x32_bf16(a.s, b2.s, acc2, 0, 0, 0);
        acc3 = __builtin_amdgcn_mfma_f32_16x16x32_bf16(a.s, b3.s, acc3, 0, 0, 0);
    }
    __syncthreads();   // xls reads done; safe to overlay ls
    int r4 = (lane >> 4) * 4;
#pragma unroll
    for (int r = 0; r < 4; r++) {
        ls[w][r4 + r][0 * 16 + (lane & 15)] = acc0[r];
        ls[w][r4 + r][1 * 16 + (lane & 15)] = acc1[r];
        ls[w][r4 + r][2 * 16 + (lane & 15)] = acc2[r];
        ls[w][r4 + r][3 * 16 + (lane & 15)] = acc3[r];
    }
    __syncthreads();
    int prow = lane >> 2, cg = lane & 3;
    int row = row0 + w * 16 + prow;
    if (row < N) {
        float dv = dinv[row];
        const float* lr = &ls[w][prow][cg * 16];
        uint4 o;
        o.x = pack4_fp8(lr[0] * dv, lr[1] * dv, lr[2] * dv, lr[3] * dv);
        o.y = pack4_fp8(lr[4] * dv, lr[5] * dv, lr[6] * dv, lr[7] * dv);
        o.z = pack4_fp8(lr[8] * dv, lr[9] * dv, lr[10] * dv, lr[11] * dv);
        o.w = pack4_fp8(lr[12] * dv, lr[13] * dv, lr[14] * dv, lr[15] * dv);
        if (cg < 2) ((uint4*)(hsA + (size_t)row * 8))[cg] = o;
        else        ((uint4*)(hsB + (size_t)row * 8))[cg - 2] = o;
    }
}

// ---------------- MFMA GEMM layer 2: buf bf16 [N][64] @ W2 -> fp8 half rows ----------------
__global__ void gemm2_mfma(const unsigned int* __restrict__ in, int K, int H,
                           const unsigned short* __restrict__ w2t,
                           const float* __restrict__ dinv,
                           unsigned int* __restrict__ hsA,
                           unsigned int* __restrict__ hsB, int N) {
    const int KP = 64;
    __shared__ float ls[4][16][64];   // 16384 B
    int tid = threadIdx.x;
    int w = tid >> 6, lane = tid & 63;
    int row0 = blockIdx.x * 64 + w * 16;

    int arow = row0 + (lane & 15);
    int kgrp = (lane >> 4) * 8;
    f32x4 acc0 = 0.0f, acc1 = 0.0f, acc2 = 0.0f, acc3 = 0.0f;
#pragma unroll
    for (int k0 = 0; k0 < KP; k0 += 32) {
        int koff = k0 + kgrp;
        ABfrag a; a.u[0] = 0; a.u[1] = 0; a.u[2] = 0; a.u[3] = 0;
        if (arow < N) {
            uint4 v = *(const uint4*)(in + (size_t)arow * 32 + (koff >> 1));  // 8 bf16
            a.u[0] = v.x; a.u[1] = v.y; a.u[2] = v.z; a.u[3] = v.w;
        }
        ABfrag b0, b1, b2, b3;
        b0.s = *(const short8v*)&w2t[(0 * 16 + (lane & 15)) * 72 + koff];
        b1.s = *(const short8v*)&w2t[(1 * 16 + (lane & 15)) * 72 + koff];
        b2.s = *(const short8v*)&w2t[(2 * 16 + (lane & 15)) * 72 + koff];
        b3.s = *(const short8v*)&w2t[(3 * 16 + (lane & 15)) * 72 + koff];
        acc0 = __builtin_amdgcn_mfma_f32_16x16x32_bf16(a.s, b0.s, acc0, 0, 0, 0);
        acc1 = __builtin_amdgcn_mfma_f32_16x16x32_bf16(a.s, b1.s, acc1, 0, 0, 0);
        acc2 = __builtin_amdgcn_mfma_f32_16x16x32_bf16(a.s, b2.s, acc2, 0, 0, 0);
        acc3 = __builtin_amdgcn_mfma_f32_16x16x32_bf16(a.s, b3.s, acc3, 0, 0, 0);
    }
    int r4 = (lane >> 4) * 4;
#pragma unroll
    for (int r = 0; r < 4; r++) {
        ls[w][r4 + r][0 * 16 + (lane & 15)] = acc0[r];
        ls[w][r4 + r][1 * 16 + (lane & 15)] = acc1[r];
        ls[w][r4 + r][2 * 16 + (lane & 15)] = acc2[r];
        ls[w][r4 + r][3 * 16 + (lane & 15)] = acc3[r];
    }
    __syncthreads();
    int prow = lane >> 2, cg = lane & 3;
    int row = row0 + prow;
    if (row < N) {
        float dv = dinv[row];
        const float* lr = &ls[w][prow][cg * 16];
        uint4 o;
        o.x = pack4_fp8(lr[0] * dv, lr[1] * dv, lr[2] * dv, lr[3] * dv);
        o.y = pack4_fp8(lr[4] * dv, lr[5] * dv, lr[6] * dv, lr[7] * dv);
        o.z = pack4_fp8(lr[8] * dv, lr[9] * dv, lr[10] * dv, lr[11] * dv);
        o.w = pack4_fp8(lr[12] * dv, lr[13] * dv, lr[14] * dv, lr[15] * dv);
        if (cg < 2) ((uint4*)(hsA + (size_t)row * 8))[cg] = o;
        else        ((uint4*)(hsB + (size_t)row * 8))[cg - 2] = o;
    }
}

// ---------------- aggregation over one fp8 half (32B rows, L2-resident) ----------------
__global__ void agg_half_kernel(const unsigned int* __restrict__ hsh,
                                const int* __restrict__ rowptr, const int* __restrict__ colidx,
                                const float* __restrict__ dinv, const float* __restrict__ bias,
                                int cbase, unsigned int* __restrict__ outbuf, int N) {
    int t = blockIdx.x * blockDim.x + threadIdx.x;
    int node = t >> 3;
    int q = t & 7;
    if (node >= N) return;
    const unsigned int* basq = hsh + q;
    unsigned int sv = basq[(size_t)node * 8];   // self loop term
    floatx2 plo = __builtin_amdgcn_cvt_pk_f32_fp8((int)sv, false);
    floatx2 phi = __builtin_amdgcn_cvt_pk_f32_fp8((int)sv, true);
    float a0 = plo[0], a1 = plo[1], a2 = phi[0], a3 = phi[1];
    int beg = rowptr[node], end = rowptr[node + 1];
    int e = beg;
    for (; e < end && (e & 3); e++) {
        unsigned int v0 = basq[(size_t)colidx[e] * 8];
        floatx2 l0 = __builtin_amdgcn_cvt_pk_f32_fp8((int)v0, false);
        floatx2 h0 = __builtin_amdgcn_cvt_pk_f32_fp8((int)v0, true);
        a0 += l0[0]; a1 += l0[1]; a2 += h0[0]; a3 += h0[1];
    }
    for (; e + 8 <= end; e += 8) {
        int4 c0 = *(const int4*)(colidx + e);
        int4 c1 = *(const int4*)(colidx + e + 4);
        unsigned int v0 = basq[(size_t)c0.x * 8];
        unsigned int v1 = basq[(size_t)c0.y * 8];
        unsigned int v2 = basq[(size_t)c0.z * 8];
        unsigned int v3 = basq[(size_t)c0.w * 8];
        unsigned int v4 = basq[(size_t)c1.x * 8];
        unsigned int v5 = basq[(size_t)c1.y * 8];
        unsigned int v6 = basq[(size_t)c1.z * 8];
        unsigned int v7 = basq[(size_t)c1.w * 8];
        floatx2 l0 = __builtin_amdgcn_cvt_pk_f32_fp8((int)v0, false);
        floatx2 h0 = __builtin_amdgcn_cvt_pk_f32_fp8((int)v0, true);
        floatx2 l1 = __builtin_amdgcn_cvt_pk_f32_fp8((int)v1, false);
        floatx2 h1 = __builtin_amdgcn_cvt_pk_f32_fp8((int)v1, true);
        floatx2 l2 = __builtin_amdgcn_cvt_pk_f32_fp8((int)v2, false);
        floatx2 h2 = __builtin_amdgcn_cvt_pk_f32_fp8((int)v2, true);
        floatx2 l3 = __builtin_amdgcn_cvt_pk_f32_fp8((int)v3, false);
        floatx2 h3 = __builtin_amdgcn_cvt_pk_f32_fp8((int)v3, true);
        floatx2 l4 = __builtin_amdgcn_cvt_pk_f32_fp8((int)v4, false);
        floatx2 h4 = __builtin_amdgcn_cvt_pk_f32_fp8((int)v4, true);
        floatx2 l5 = __builtin_amdgcn_cvt_pk_f32_fp8((int)v5, false);
        floatx2 h5 = __builtin_amdgcn_cvt_pk_f32_fp8((int)v5, true);
        floatx2 l6 = __builtin_amdgcn_cvt_pk_f32_fp8((int)v6, false);
        floatx2 h6 = __builtin_amdgcn_cvt_pk_f32_fp8((int)v6, true);
        floatx2 l7 = __builtin_amdgcn_cvt_pk_f32_fp8((int)v7, false);
        floatx2 h7 = __builtin_amdgcn_cvt_pk_f32_fp8((int)v7, true);
        a0 += ((l0[0] + l1[0]) + (l2[0] + l3[0])) + ((l4[0] + l5[0]) + (l6[0] + l7[0]));
        a1 += ((l0[1] + l1[1]) + (l2[1] + l3[1])) + ((l4[1] + l5[1]) + (l6[1] + l7[1]));
        a2 += ((h0[0] + h1[0]) + (h2[0] + h3[0])) + ((h4[0] + h5[0]) + (h6[0] + h7[0]));
        a3 += ((h0[1] + h1[1]) + (h2[1] + h3[1])) + ((h4[1] + h5[1]) + (h6[1] + h7[1]));
    }
    if (e + 4 <= end) {
        int4 c0 = *(const int4*)(colidx + e);
        unsigned int v0 = basq[(size_t)c0.x * 8];
        unsigned int v1 = basq[(size_t)c0.y * 8];
        unsigned int v2 = basq[(size_t)c0.z * 8];
        unsigned int v3 = basq[(size_t)c0.w * 8];
        floatx2 l0 = __builtin_amdgcn_cvt_pk_f32_fp8((int)v0, false);
        floatx2 h0 = __builtin_amdgcn_cvt_pk_f32_fp8((int)v0, true);
        floatx2 l1 = __builtin_amdgcn_cvt_pk_f32_fp8((int)v1, false);
        floatx2 h1 = __builtin_amdgcn_cvt_pk_f32_fp8((int)v1, true);
        floatx2 l2 = __builtin_amdgcn_cvt_pk_f32_fp8((int)v2, false);
        floatx2 h2 = __builtin_amdgcn_cvt_pk_f32_fp8((int)v2, true);
        floatx2 l3 = __builtin_amdgcn_cvt_pk_f32_fp8((int)v3, false);
        floatx2 h3 = __builtin_amdgcn_cvt_pk_f32_fp8((int)v3, true);
        a0 += (l0[0] + l1[0]) + (l2[0] + l3[0]);
        a1 += (l0[1] + l1[1]) + (l2[1] + l3[1]);
        a2 += (h0[0] + h1[0]) + (h2[0] + h3[0]);
        a3 += (h0[1] + h1[1]) + (h2[1] + h3[1]);
        e += 4;
    }
    for (; e < end; e++) {
        unsigned int v0 = basq[(size_t)colidx[e] * 8];
        floatx2 l0 = __builtin_amdgcn_cvt_pk_f32_fp8((int)v0, false);
        floatx2 h0 = __builtin_amdgcn_cvt_pk_f32_fp8((int)v0, true);
        a0 += l0[0]; a1 += l0[1]; a2 += h0[0]; a3 += h0[1];
    }
    float dv = dinv[node];
    int c0 = cbase + q * 4;
    float b0 = (c0 + 0 < HH) ? bias[c0 + 0] : 0.0f;
    float b1 = (c0 + 1 < HH) ? bias[c0 + 1] : 0.0f;
    float b2 = (c0 + 2 < HH) ? bias[c0 + 2] : 0.0f;
    float b3 = (c0 + 3 < HH) ? bias[c0 + 3] : 0.0f;
    float r0 = fmaxf(a0 * dv + b0, 0.0f);
    float r1 = fmaxf(a1 * dv + b1, 0.0f);
    float r2 = fmaxf(a2 * dv + b2, 0.0f);
    float r3 = fmaxf(a3 * dv + b3, 0.0f);
    uint2 w;
    if (c0 >= HH) { w.x = 0u; w.y = 0u; }
    else { w.x = f2bf_pair(r0, r1); w.y = f2bf_pair(r2, r3); }
    ((uint2*)outbuf)[(size_t)node * 16 + (cbase >> 2) + q] = w;
}

// ---------------- pooling + head over bf16 rows (bounds searched inline) ----------------
__global__ void pool_head_kernel(const unsigned int* __restrict__ h,
                                 const int* __restrict__ batch, int N,
                                 const float* __restrict__ Wl, const float* __restrict__ bl,
                                 float* __restrict__ out, int G) {
    __shared__ float4 red[16][16];    // [sub][q]
    int b = blockIdx.x;
    int t = threadIdx.x;
    int sub = t >> 4, q = t & 15;
    int beg, end;
    {
        int lo = 0, hi = N;
        while (lo < hi) { int mid = (lo + hi) >> 1; if (batch[mid] < b) lo = mid + 1; else hi = mid; }
        beg = lo;
        lo = 0; hi = N;
        while (lo < hi) { int mid = (lo + hi) >> 1; if (batch[mid] < b + 1) lo = mid + 1; else hi = mid; }
        end = lo;
    }
    const uint2* base = (const uint2*)h;
    float4 acc = make_float4(0.f, 0.f, 0.f, 0.f);
    for (int node = beg + sub; node < end; node += 16) {
        uint2 v = base[(size_t)node * 16 + q];
        acc.x += bf_lo(v.x); acc.y += bf_hi(v.x); acc.z += bf_lo(v.y); acc.w += bf_hi(v.y);
    }
    red[sub][q] = acc;
    __syncthreads();
#pragma unroll
    for (int off = 8; off >= 1; off >>= 1) {
        if (sub < off) {
            float4 a = red[sub][q], c = red[sub + off][q];
            a.x += c.x; a.y += c.y; a.z += c.z; a.w += c.w;
            red[sub][q] = a;
        }
        __syncthreads();
    }
    if (t == 0) {
        const float* g = (const float*)&red[0][0];
        float dot = 0.0f;
        for (int c = 0; c < HH; c++) dot += g[c] * Wl[c];
        float cnt = (float)(end - beg);
        float x = dot / fmaxf(cnt, 1.0f) + bl[0];
        out[b] = 1.0f / (1.0f + expf(-x));
    }
}

extern "C" void kernel_launch(void* const* d_in, const int* in_sizes, int n_in,
                              void* d_out, int out_size, void* d_ws, size_t ws_size,
                              hipStream_t stream) {
    const float* x     = (const float*)d_in[0];
    const int*   ei    = (const int*)d_in[1];
    const int*   batch = (const int*)d_in[2];
    const float* W1    = (const float*)d_in[3];
    const float* b1    = (const float*)d_in[4];
    const float* W2    = (const float*)d_in[5];
    const float* b2    = (const float*)d_in[6];
    const float* Wl    = (const float*)d_in[7];
    const float* bl    = (const float*)d_in[8];
    float* out = (float*)d_out;

    int N = in_sizes[2];
    int E = in_sizes[1] / 2;
    int F = in_sizes[0] / N;       // 136
    int G = out_size;              // 256 graphs

    int NB = (N + BSZ - 1) >> BSH;    // ~391 buckets
    int NC = (E + CH - 1) / CH;       // ~391 chunks
    int M  = NB * NC;
    int NS = (M + SCH - 1) / SCH;     // <=64 for this size

    char* ws = (char*)d_ws;
    size_t off = 0;
    auto alloc = [&](size_t bytes) -> void* {
        void* p = ws + off;
        off += (bytes + 255) & ~(size_t)255;
        return p;
    };
    size_t halfBytes = (size_t)N * 32;       // fp8 half rows (32B)
    size_t bufBytes  = (size_t)N * 128;      // bf16 rows (128B)
    size_t ebufBytes = (size_t)E * 4;
    float*          dinv      = (float*)alloc((size_t)N * 4);
    int*            rowptr    = (int*)alloc((size_t)(N + 1) * 4);
    int*            colidx    = (int*)alloc(ebufBytes);
    unsigned int*   hsA       = (unsigned int*)alloc(halfBytes);
    unsigned int*   hsB       = (unsigned int*)alloc(halfBytes);
    unsigned int*   buf       = (unsigned int*)alloc(bufBytes > ebufBytes ? bufBytes : ebufBytes);
    int*            blockHist = (int*)alloc((size_t)M * 4);
    int*            scanned   = (int*)alloc((size_t)M * 4);
    int*            csum      = (int*)alloc((size_t)NS * 4 + 256);
    unsigned short* w1t       = (unsigned short*)alloc(64 * 168 * 2);
    unsigned short* w2t       = (unsigned short*)alloc(64 * 72 * 2);
    int*            ebuf      = (int*)buf;    // alias: dead before first agg writes buf

    // CSR build (by dst), no global atomics; scan2 block 0 + prepW blocks 1..60
    histA_kernel<<<NC, 256, 0, stream>>>(ei, E, NB, NC, blockHist);
    scan1_kernel<<<NS, 256, 0, stream>>>(blockHist, M, csum);
    scan2_prepW_kernel<<<61, 256, 0, stream>>>(csum, NS, rowptr, N, E,
                                               W1, F, HH, W2, HH, w1t, w2t);
    scan3_kernel<<<NS, 256, 0, stream>>>(blockHist, M, csum, scanned);
    scatterB_kernel<<<NC, 512, 0, stream>>>(ei, E, NB, NC, blockHist, scanned, ebuf);
    buildC_kernel<<<NB, 512, 0, stream>>>(ebuf, scanned, NB, NC, N, E, rowptr, dinv, colidx);

    int aggBlocks = ((N * 8) + 255) / 256;
    int mfmaBlocks = (N + 63) / 64;

    // layer 1
    gemm1_mfma<<<mfmaBlocks, 256, 0, stream>>>(x, F, HH, w1t, dinv, hsA, hsB, N);
    agg_half_kernel<<<aggBlocks, 256, 0, stream>>>(hsA, rowptr, colidx, dinv, b1, 0,  buf, N);
    agg_half_kernel<<<aggBlocks, 256, 0, stream>>>(hsB, rowptr, colidx, dinv, b1, 32, buf, N);

    // layer 2
    gemm2_mfma<<<mfmaBlocks, 256, 0, stream>>>(buf, HH, HH, w2t, dinv, hsA, hsB, N);
    agg_half_kernel<<<aggBlocks, 256, 0, stream>>>(hsA, rowptr, colidx, dinv, b2, 0,  buf, N);
    agg_half_kernel<<<aggBlocks, 256, 0, stream>>>(hsB, rowptr, colidx, dinv, b2, 32, buf, N);

    // pooling + fused head
    pool_head_kernel<<<G, 256, 0, stream>>>(buf, batch, N, Wl, bl, out, G);
}